// Round 9
// baseline (606.202 us; speedup 1.0000x reference)
//
#include <hip/hip_runtime.h>

constexpr int N_NODES = 50000;
constexpr int N_EDGES = 800000;
constexpr int ND  = 32;
constexpr int ED  = 16;
constexpr int HID = 96;
constexpr int NLAYER = 3;

typedef unsigned short ushort_t;
typedef unsigned int uint_t;
typedef __attribute__((ext_vector_type(8))) short bf16x8;
typedef __attribute__((ext_vector_type(4))) float f32x4;

__device__ __forceinline__ float bf2f(ushort_t u) {
    union { float f; uint_t ui; } c; c.ui = ((uint_t)u) << 16; return c.f;
}
__device__ __forceinline__ ushort_t f2bf(float f) {
    uint_t u = __float_as_uint(f);
    return (ushort_t)((u + 0x7FFFu + ((u >> 16) & 1u)) >> 16);  // RNE
}

// ---------------- CSR build (by dst), once per call ----------------
__global__ void k_count_deg(const int* __restrict__ dst, int* __restrict__ deg) {
    int e = blockIdx.x * 256 + threadIdx.x;
    if (e < N_EDGES) atomicAdd(&deg[dst[e]], 1);
}

__global__ void k_scan_block(const int* __restrict__ deg, int* __restrict__ rowptr,
                             int* __restrict__ bsum) {
    __shared__ int s[256];
    int i = blockIdx.x * 256 + threadIdx.x;
    int v = (i < N_NODES) ? deg[i] : 0;
    s[threadIdx.x] = v;
    __syncthreads();
    for (int off = 1; off < 256; off <<= 1) {
        int t = (threadIdx.x >= off) ? s[threadIdx.x - off] : 0;
        __syncthreads();
        s[threadIdx.x] += t;
        __syncthreads();
    }
    if (i < N_NODES) rowptr[i] = s[threadIdx.x] - v;
    if (threadIdx.x == 255) bsum[blockIdx.x] = s[255];
}

__global__ void k_scan_bsum(int* __restrict__ bsum, int nb) {
    __shared__ int s[256];
    int t = threadIdx.x;
    int v = (t < nb) ? bsum[t] : 0;
    s[t] = v;
    __syncthreads();
    for (int off = 1; off < 256; off <<= 1) {
        int tv = (t >= off) ? s[t - off] : 0;
        __syncthreads();
        s[t] += tv;
        __syncthreads();
    }
    if (t < nb) bsum[t] = s[t] - v;
}

// also initializes the scatter cursor (fill = rowptr)
__global__ void k_scan_add(int* __restrict__ rowptr, const int* __restrict__ bsum,
                           int* __restrict__ fill) {
    int i = blockIdx.x * 256 + threadIdx.x;
    if (i < N_NODES) {
        int v = rowptr[i] + bsum[blockIdx.x];
        rowptr[i] = v;
        fill[i] = v;
    }
    if (i == 0) rowptr[N_NODES] = N_EDGES;
}

// ---- scatter: 4B payload (edge id only) -> half the write-line allocates ----
__global__ void k_scatter(const int* __restrict__ dst, int* __restrict__ fill,
                          int* __restrict__ csre) {
    int e = blockIdx.x * 256 + threadIdx.x;
    if (e >= N_EDGES) return;
    int d = dst[e];
    int pos = atomicAdd(&fill[d], 1);
    csre[pos] = e;
}

// ---- gather pass: random READS (L3-absorbed), sequential writes.
// Builds srcs/pdst/ea_csr in CSR order. ----
__global__ void k_gather(const int* __restrict__ csre, const int* __restrict__ srcA,
                         const int* __restrict__ dstA, const float* __restrict__ eattr,
                         int* __restrict__ srcs, int* __restrict__ pdst,
                         ushort_t* __restrict__ ea) {
    int p = blockIdx.x * 256 + threadIdx.x;
    if (p >= N_EDGES) return;
    int e = csre[p];
    srcs[p] = srcA[e];
    pdst[p] = dstA[e];
    const float4* er = (const float4*)(eattr + (size_t)e * ED);
    float4 v0 = er[0], v1 = er[1], v2 = er[2], v3 = er[3];
    uint4 w0, w1;
    w0.x = (uint_t)f2bf(v0.x) | ((uint_t)f2bf(v0.y) << 16);
    w0.y = (uint_t)f2bf(v0.z) | ((uint_t)f2bf(v0.w) << 16);
    w0.z = (uint_t)f2bf(v1.x) | ((uint_t)f2bf(v1.y) << 16);
    w0.w = (uint_t)f2bf(v1.z) | ((uint_t)f2bf(v1.w) << 16);
    w1.x = (uint_t)f2bf(v2.x) | ((uint_t)f2bf(v2.y) << 16);
    w1.y = (uint_t)f2bf(v2.z) | ((uint_t)f2bf(v2.w) << 16);
    w1.z = (uint_t)f2bf(v3.x) | ((uint_t)f2bf(v3.y) << 16);
    w1.w = (uint_t)f2bf(v3.z) | ((uint_t)f2bf(v3.w) << 16);
    uint4* ew = (uint4*)(ea + (size_t)p * ED);
    ew[0] = w0;
    ew[1] = w1;
}

// ---------------- proj: h = x @ proj_w + proj_b  (K=32) ----------------
__global__ __launch_bounds__(192) void k_proj(const float* __restrict__ x,
                                              const float* __restrict__ pw,
                                              const float* __restrict__ pb,
                                              float* __restrict__ h) {
    int t = threadIdx.x;
    int c = t % 96, half = t / 96;
    float wreg[ND];
#pragma unroll
    for (int k = 0; k < ND; k++) wreg[k] = pw[k * HID + c];
    float b = pb[c];
    int n0 = blockIdx.x * 16 + half * 8;
    for (int i = 0; i < 8; i += 2) {
        int na = n0 + i, nb = na + 1;
        const float4* xa = (const float4*)(x + (size_t)na * ND);
        const float4* xb = (const float4*)(x + (size_t)nb * ND);
        float accA = b, accB = b;
#pragma unroll
        for (int k4 = 0; k4 < ND / 4; k4++) {
            float4 va = xa[k4], vb = xb[k4];
            accA += va.x * wreg[4 * k4] + va.y * wreg[4 * k4 + 1] +
                    va.z * wreg[4 * k4 + 2] + va.w * wreg[4 * k4 + 3];
            accB += vb.x * wreg[4 * k4] + vb.y * wreg[4 * k4 + 1] +
                    vb.z * wreg[4 * k4 + 2] + vb.w * wreg[4 * k4 + 3];
        }
        h[(size_t)na * HID + c] = accA;
        h[(size_t)nb * HID + c] = accB;
    }
}

// ---- k_linlr_mfma: [xl|xr] = h @ [Wl|Wr] + [bl|br], bf16 out, MFMA ----
__global__ __launch_bounds__(256) void k_linlr_mfma(
    const float* __restrict__ h, const float* __restrict__ Wl,
    const float* __restrict__ bl, const float* __restrict__ Wr,
    const float* __restrict__ br, ushort_t* __restrict__ xl,
    ushort_t* __restrict__ xr) {
    __shared__ ushort_t sW[192 * 104];
    __shared__ float sB[192];
    int t = threadIdx.x;

    for (int idx = t; idx < 192 * 96; idx += 256) {
        int n = idx % 192, k = idx / 192;
        float v = (n < 96) ? Wl[k * 96 + n] : Wr[k * 96 + (n - 96)];
        sW[n * 104 + k] = f2bf(v);
    }
    if (t < 192) sB[t] = (t < 96) ? bl[t] : br[t - 96];
    __syncthreads();

    int wv = t >> 6, lane = t & 63;
    int m0 = blockIdx.x * 64 + wv * 16;
    if (m0 >= N_NODES) return;
    int m = lane & 15, quad = lane >> 4;

    bf16x8 afr[3];
    const float* hrow = h + (size_t)(m0 + m) * HID;
#pragma unroll
    for (int s = 0; s < 3; s++) {
        float4 v0 = *(const float4*)(hrow + s * 32 + quad * 8);
        float4 v1 = *(const float4*)(hrow + s * 32 + quad * 8 + 4);
        bf16x8 a;
        a[0] = (short)f2bf(v0.x); a[1] = (short)f2bf(v0.y);
        a[2] = (short)f2bf(v0.z); a[3] = (short)f2bf(v0.w);
        a[4] = (short)f2bf(v1.x); a[5] = (short)f2bf(v1.y);
        a[6] = (short)f2bf(v1.z); a[7] = (short)f2bf(v1.w);
        afr[s] = a;
    }

#pragma unroll
    for (int nt = 0; nt < 12; nt++) {
        int ch = nt * 16 + m;
        f32x4 acc = {0.f, 0.f, 0.f, 0.f};
#pragma unroll
        for (int s = 0; s < 3; s++) {
            bf16x8 bfr = *(const bf16x8*)(sW + (nt * 16 + m) * 104 + s * 32 + quad * 8);
            acc = __builtin_amdgcn_mfma_f32_16x16x32_bf16(afr[s], bfr, acc, 0, 0, 0);
        }
        float bias = sB[ch];
        ushort_t* dst = (ch < 96) ? (xl + (size_t)(m0 + quad * 4) * HID + ch)
                                  : (xr + (size_t)(m0 + quad * 4) * HID + (ch - 96));
#pragma unroll
        for (int r = 0; r < 4; r++)
            dst[(size_t)r * HID] = f2bf(acc[r] + bias);
    }
}

// ---- k_ev: edge-parallel attention weights via MFMA, CSR order, pipelined ----
__global__ __launch_bounds__(256) void k_ev(
    const ushort_t* __restrict__ xlb, const ushort_t* __restrict__ xrb,
    const ushort_t* __restrict__ ea, const int* __restrict__ srcs,
    const int* __restrict__ pdst, const float* __restrict__ WeL,
    const float* __restrict__ attL, float4* __restrict__ ev) {
    int wid = blockIdx.x * 4 + (threadIdx.x >> 6);
    int lane = threadIdx.x & 63;
    if (wid >= N_EDGES / 128) return;
    int col = lane & 15, quad = lane >> 4;
    int comp = col & 1, base = col >> 1;

    // preload this wave's 128 srcs/pdst values (2 per lane)
    int2 sp = *(const int2*)(srcs + wid * 128 + 2 * lane);
    int2 dp = *(const int2*)(pdst + wid * 128 + 2 * lane);

    // wave-invariant A fragments (We^T) and att values
    bf16x8 afr[6];
#pragma unroll
    for (int mc = 0; mc < 6; mc++) {
        bf16x8 a = {0, 0, 0, 0, 0, 0, 0, 0};
        if (quad < 2) {
#pragma unroll
            for (int j = 0; j < 8; j++)
                a[j] = (short)f2bf(WeL[(quad * 8 + j) * HID + mc * 16 + col]);
        }
        afr[mc] = a;
    }
    float attr[6][4];
#pragma unroll
    for (int mc = 0; mc < 6; mc++)
#pragma unroll
        for (int r = 0; r < 4; r++)
            attr[mc][r] = attL[mc * 16 + quad * 4 + r];

    // pipeline registers (2 batches in flight)
    bf16x8 bfr[2];
    uint2 xu[2][6], ru[2][6];

    auto getsd = [&](int b, int& sv, int& dv) {
        int sl = b * 8 + base;
        int sx = __shfl(sp.x, sl), sy = __shfl(sp.y, sl);
        int dx = __shfl(dp.x, sl), dy = __shfl(dp.y, sl);
        sv = comp ? sy : sx;
        dv = comp ? dy : dx;
    };
    auto issue = [&](int b, int pp) {
        int sv, dv;
        getsd(b, sv, dv);
        int p = wid * 128 + b * 16 + col;
        bf16x8 z8 = {0, 0, 0, 0, 0, 0, 0, 0};
        bfr[pp] = (quad < 2) ? *(const bf16x8*)(ea + (size_t)p * ED + quad * 8) : z8;
        const ushort_t* xp = xlb + (size_t)sv * HID + quad * 4;
        const ushort_t* rp = xrb + (size_t)dv * HID + quad * 4;
#pragma unroll
        for (int mc = 0; mc < 6; mc++) {
            xu[pp][mc] = *(const uint2*)(xp + mc * 16);
            ru[pp][mc] = *(const uint2*)(rp + mc * 16);
        }
    };

    issue(0, 0);
#pragma unroll
    for (int b = 0; b < 8; b++) {
        int pp = b & 1;
        if (b < 7) issue(b + 1, pp ^ 1);

        f32x4 zero4 = {0.f, 0.f, 0.f, 0.f};
        f32x4 d[6];
#pragma unroll
        for (int mc = 0; mc < 6; mc++)
            d[mc] = __builtin_amdgcn_mfma_f32_16x16x32_bf16(afr[mc], bfr[pp], zero4, 0, 0, 0);

        float s[6];
#pragma unroll
        for (int mc = 0; mc < 6; mc++) {
            uint2 a = xu[pp][mc], r = ru[pp][mc];
            float x0 = bf2f((ushort_t)(a.x & 0xffff)), x1 = bf2f((ushort_t)(a.x >> 16));
            float x2 = bf2f((ushort_t)(a.y & 0xffff)), x3 = bf2f((ushort_t)(a.y >> 16));
            float r0 = bf2f((ushort_t)(r.x & 0xffff)), r1 = bf2f((ushort_t)(r.x >> 16));
            float r2 = bf2f((ushort_t)(r.y & 0xffff)), r3 = bf2f((ushort_t)(r.y >> 16));
            float z0 = x0 + r0 + d[mc][0]; z0 = z0 > 0.f ? z0 : 0.2f * z0;
            float z1 = x1 + r1 + d[mc][1]; z1 = z1 > 0.f ? z1 : 0.2f * z1;
            float z2 = x2 + r2 + d[mc][2]; z2 = z2 > 0.f ? z2 : 0.2f * z2;
            float z3 = x3 + r3 + d[mc][3]; z3 = z3 > 0.f ? z3 : 0.2f * z3;
            s[mc] = z0 * attr[mc][0] + z1 * attr[mc][1] +
                    z2 * attr[mc][2] + z3 * attr[mc][3];
        }
        float U[6], V[6];
#pragma unroll
        for (int mc = 0; mc < 6; mc++) {
            U[mc] = s[mc] + __shfl_xor(s[mc], 16);
            V[mc] = U[mc] + __shfl_xor(U[mc], 32);
        }
        if (quad == 0) {
            float h0 = V[0] + U[1];
            float h1 = (V[1] - U[1]) + V[2];
            float h2 = V[3] + U[4];
            float h3 = (V[4] - U[4]) + V[5];
            int p = wid * 128 + b * 16 + col;
            ev[p] = make_float4(__expf(h0), __expf(h1), __expf(h2), __expf(h3));
        }
    }
}

// ---- k_agg: weighted sum + residual + LayerNorm (CSR order, ev sequential) ----
__global__ __launch_bounds__(256) void k_agg(
    const ushort_t* __restrict__ xlb, const float* __restrict__ evf,
    const int* __restrict__ srcs, const int* __restrict__ rowptr,
    const float* __restrict__ convb, const float* __restrict__ lng,
    const float* __restrict__ lnb, float* __restrict__ h) {
    int lane = threadIdx.x & 63;
    int node = blockIdx.x * 4 + (threadIdx.x >> 6);
    int slot = lane >> 4, q = lane & 15;
    int c0 = q * 6, head = q >> 2;
    int beg = rowptr[node], end = rowptr[node + 1];
    int cnt = (end - beg + 3) >> 2;

    float n0 = 0.f, n1 = 0.f, n2 = 0.f, n3 = 0.f, n4 = 0.f, n5 = 0.f, den = 0.f;
    if (cnt > 0) {
        int p = beg + slot;
        bool v = p < end;
        int pc = v ? p : beg;
        int src = srcs[pc];
        float evv = evf[4 * pc + head];
        const ushort_t* xp = xlb + (size_t)src * HID + c0;
        uint_t a0 = *(const uint_t*)(xp);
        uint_t a1 = *(const uint_t*)(xp + 2);
        uint_t a2 = *(const uint_t*)(xp + 4);
        for (int it = 0; it < cnt; ++it) {
            int pn = beg + (it + 1) * 4 + slot;
            bool vn = pn < end;
            int pcn = vn ? pn : beg;
            int srcn = srcs[pcn];
            float evn = evf[4 * pcn + head];
            const ushort_t* xpn = xlb + (size_t)srcn * HID + c0;
            uint_t b0 = *(const uint_t*)(xpn);
            uint_t b1 = *(const uint_t*)(xpn + 2);
            uint_t b2 = *(const uint_t*)(xpn + 4);

            float e = v ? evv : 0.f;
            n0 += e * bf2f((ushort_t)(a0 & 0xffff));
            n1 += e * bf2f((ushort_t)(a0 >> 16));
            n2 += e * bf2f((ushort_t)(a1 & 0xffff));
            n3 += e * bf2f((ushort_t)(a1 >> 16));
            n4 += e * bf2f((ushort_t)(a2 & 0xffff));
            n5 += e * bf2f((ushort_t)(a2 >> 16));
            den += e;

            v = vn; evv = evn; a0 = b0; a1 = b1; a2 = b2;
        }
    }
    n0 += __shfl_xor(n0, 16); n0 += __shfl_xor(n0, 32);
    n1 += __shfl_xor(n1, 16); n1 += __shfl_xor(n1, 32);
    n2 += __shfl_xor(n2, 16); n2 += __shfl_xor(n2, 32);
    n3 += __shfl_xor(n3, 16); n3 += __shfl_xor(n3, 32);
    n4 += __shfl_xor(n4, 16); n4 += __shfl_xor(n4, 32);
    n5 += __shfl_xor(n5, 16); n5 += __shfl_xor(n5, 32);
    den += __shfl_xor(den, 16); den += __shfl_xor(den, 32);

    size_t nb = (size_t)node * HID + c0;
    float inv = 1.f / (den + 1e-16f);
    float v0 = h[nb + 0] + n0 * inv + convb[c0 + 0];
    float v1 = h[nb + 1] + n1 * inv + convb[c0 + 1];
    float v2 = h[nb + 2] + n2 * inv + convb[c0 + 2];
    float v3 = h[nb + 3] + n3 * inv + convb[c0 + 3];
    float v4 = h[nb + 4] + n4 * inv + convb[c0 + 4];
    float v5 = h[nb + 5] + n5 * inv + convb[c0 + 5];
    float sm = v0 + v1 + v2 + v3 + v4 + v5;
    sm += __shfl_xor(sm, 1); sm += __shfl_xor(sm, 2);
    sm += __shfl_xor(sm, 4); sm += __shfl_xor(sm, 8);
    float mu = sm * (1.f / 96.f);
    float d0 = v0 - mu, d1 = v1 - mu, d2 = v2 - mu;
    float d3 = v3 - mu, d4 = v4 - mu, d5 = v5 - mu;
    float sv = d0 * d0 + d1 * d1 + d2 * d2 + d3 * d3 + d4 * d4 + d5 * d5;
    sv += __shfl_xor(sv, 1); sv += __shfl_xor(sv, 2);
    sv += __shfl_xor(sv, 4); sv += __shfl_xor(sv, 8);
    float rstd = rsqrtf(sv * (1.f / 96.f) + 1e-5f);
    if (slot == 0) {
        h[nb + 0] = d0 * rstd * lng[c0 + 0] + lnb[c0 + 0];
        h[nb + 1] = d1 * rstd * lng[c0 + 1] + lnb[c0 + 1];
        h[nb + 2] = d2 * rstd * lng[c0 + 2] + lnb[c0 + 2];
        h[nb + 3] = d3 * rstd * lng[c0 + 3] + lnb[c0 + 3];
        h[nb + 4] = d4 * rstd * lng[c0 + 4] + lnb[c0 + 4];
        h[nb + 5] = d5 * rstd * lng[c0 + 5] + lnb[c0 + 5];
    }
}

// ---- k_head_mfma: out = gelu(h@W1+b1)@W2+b2 via MFMA ----
__global__ __launch_bounds__(256) void k_head_mfma(
    const float* __restrict__ h, const float* __restrict__ W1,
    const float* __restrict__ b1, const float* __restrict__ W2,
    const float* __restrict__ b2, float* __restrict__ out) {
    __shared__ ushort_t sW[48 * 104];
    __shared__ float sB1[48];
    __shared__ float sW2[48];
    int t = threadIdx.x;
    for (int idx = t; idx < 48 * 96; idx += 256) {
        int j = idx % 48, k = idx / 48;
        sW[j * 104 + k] = f2bf(W1[k * 48 + j]);
    }
    if (t < 48) { sB1[t] = b1[t]; sW2[t] = W2[t]; }
    __syncthreads();

    int wv = t >> 6, lane = t & 63;
    int m0 = blockIdx.x * 64 + wv * 16;
    if (m0 >= N_NODES) return;
    int col = lane & 15, quad = lane >> 4;

    bf16x8 afr[3];
    const float* hrow = h + (size_t)(m0 + col) * HID;
#pragma unroll
    for (int s = 0; s < 3; s++) {
        float4 v0 = *(const float4*)(hrow + s * 32 + quad * 8);
        float4 v1 = *(const float4*)(hrow + s * 32 + quad * 8 + 4);
        bf16x8 a;
        a[0] = (short)f2bf(v0.x); a[1] = (short)f2bf(v0.y);
        a[2] = (short)f2bf(v0.z); a[3] = (short)f2bf(v0.w);
        a[4] = (short)f2bf(v1.x); a[5] = (short)f2bf(v1.y);
        a[6] = (short)f2bf(v1.z); a[7] = (short)f2bf(v1.w);
        afr[s] = a;
    }

    const float inv_sqrt2 = 0.70710678118654752f;
    float y0 = 0.f, y1 = 0.f, y2 = 0.f, y3 = 0.f;
#pragma unroll
    for (int nt = 0; nt < 3; nt++) {
        f32x4 acc = {0.f, 0.f, 0.f, 0.f};
#pragma unroll
        for (int s = 0; s < 3; s++) {
            bf16x8 bfr = *(const bf16x8*)(sW + (nt * 16 + col) * 104 + s * 32 + quad * 8);
            acc = __builtin_amdgcn_mfma_f32_16x16x32_bf16(afr[s], bfr, acc, 0, 0, 0);
        }
        int ch = nt * 16 + col;
        float bias = sB1[ch], w2 = sW2[ch];
        float v, g;
        v = acc[0] + bias; g = 0.5f * v * (1.f + erff(v * inv_sqrt2)); y0 += g * w2;
        v = acc[1] + bias; g = 0.5f * v * (1.f + erff(v * inv_sqrt2)); y1 += g * w2;
        v = acc[2] + bias; g = 0.5f * v * (1.f + erff(v * inv_sqrt2)); y2 += g * w2;
        v = acc[3] + bias; g = 0.5f * v * (1.f + erff(v * inv_sqrt2)); y3 += g * w2;
    }
    y0 += __shfl_xor(y0, 1); y0 += __shfl_xor(y0, 2);
    y0 += __shfl_xor(y0, 4); y0 += __shfl_xor(y0, 8);
    y1 += __shfl_xor(y1, 1); y1 += __shfl_xor(y1, 2);
    y1 += __shfl_xor(y1, 4); y1 += __shfl_xor(y1, 8);
    y2 += __shfl_xor(y2, 1); y2 += __shfl_xor(y2, 2);
    y2 += __shfl_xor(y2, 4); y2 += __shfl_xor(y2, 8);
    y3 += __shfl_xor(y3, 1); y3 += __shfl_xor(y3, 2);
    y3 += __shfl_xor(y3, 4); y3 += __shfl_xor(y3, 8);
    if (col == 0) {
        float bb = b2[0];
        out[m0 + quad * 4 + 0] = y0 + bb;
        out[m0 + quad * 4 + 1] = y1 + bb;
        out[m0 + quad * 4 + 2] = y2 + bb;
        out[m0 + quad * 4 + 3] = y3 + bb;
    }
}

extern "C" void kernel_launch(void* const* d_in, const int* in_sizes, int n_in,
                              void* d_out, int out_size, void* d_ws, size_t ws_size,
                              hipStream_t stream) {
    const float* x       = (const float*)d_in[0];
    const int*   eidx    = (const int*)  d_in[1];
    const float* eattr   = (const float*)d_in[2];
    const float* proj_w  = (const float*)d_in[3];
    const float* proj_b  = (const float*)d_in[4];
    const float* lin_l_w = (const float*)d_in[5];
    const float* lin_l_b = (const float*)d_in[6];
    const float* lin_r_w = (const float*)d_in[7];
    const float* lin_r_b = (const float*)d_in[8];
    const float* lin_e_w = (const float*)d_in[9];
    const float* att     = (const float*)d_in[10];
    const float* conv_b  = (const float*)d_in[11];
    const float* ln_g    = (const float*)d_in[12];
    const float* ln_b    = (const float*)d_in[13];
    const float* head_w1 = (const float*)d_in[14];
    const float* head_b1 = (const float*)d_in[15];
    const float* head_w2 = (const float*)d_in[16];
    const float* head_b2 = (const float*)d_in[17];
    float* out = (float*)d_out;

    char* p = (char*)d_ws;
    auto alloc = [&](size_t bytes) -> char* {
        char* r = p;
        p += (bytes + 255) & ~size_t(255);
        return r;
    };
    float*    h      = (float*)alloc(sizeof(float) * (size_t)N_NODES * HID);
    ushort_t* xl     = (ushort_t*)alloc(2 * (size_t)N_NODES * HID);
    ushort_t* xr     = (ushort_t*)alloc(2 * (size_t)N_NODES * HID);
    int*      deg    = (int*)alloc(4 * (size_t)N_NODES);
    int*      fill   = (int*)alloc(4 * (size_t)N_NODES);
    int*      rowptr = (int*)alloc(4 * (size_t)(N_NODES + 1));
    int*      bsum   = (int*)alloc(4 * 256);
    int*      csre   = (int*)alloc(4 * (size_t)N_EDGES);
    int*      srcs   = (int*)alloc(4 * ((size_t)N_EDGES + 256));
    int*      pdst   = (int*)alloc(4 * ((size_t)N_EDGES + 256));
    ushort_t* ea_csr = (ushort_t*)alloc(2 * (size_t)N_EDGES * ED);
    float4*   ev     = (float4*)alloc(16 * (size_t)N_EDGES);

    const int* srcA = eidx;
    const int* dstA = eidx + N_EDGES;

    int ebl = (N_EDGES + 255) / 256;   // 3125
    int nbl = (N_NODES + 255) / 256;   // 196

    hipMemsetAsync(deg, 0, 4 * (size_t)N_NODES, stream);
    k_count_deg<<<ebl, 256, 0, stream>>>(dstA, deg);
    k_scan_block<<<nbl, 256, 0, stream>>>(deg, rowptr, bsum);
    k_scan_bsum<<<1, 256, 0, stream>>>(bsum, nbl);
    k_scan_add<<<nbl, 256, 0, stream>>>(rowptr, bsum, fill);
    k_scatter<<<ebl, 256, 0, stream>>>(dstA, fill, csre);
    k_gather<<<ebl, 256, 0, stream>>>(csre, srcA, dstA, eattr, srcs, pdst, ea_csr);

    k_proj<<<N_NODES / 16, 192, 0, stream>>>(x, proj_w, proj_b, h);
    for (int l = 0; l < NLAYER; l++) {
        k_linlr_mfma<<<(N_NODES + 63) / 64, 256, 0, stream>>>(
            h, lin_l_w + (size_t)l * HID * HID, lin_l_b + (size_t)l * HID,
            lin_r_w + (size_t)l * HID * HID, lin_r_b + (size_t)l * HID, xl, xr);
        k_ev<<<1563, 256, 0, stream>>>(xl, xr, ea_csr, srcs, pdst,
                                       lin_e_w + (size_t)l * ED * HID,
                                       att + (size_t)l * HID,
                                       (float4*)ev);
        k_agg<<<N_NODES / 4, 256, 0, stream>>>(
            xl, (const float*)ev, srcs, rowptr, conv_b + (size_t)l * HID,
            ln_g + (size_t)l * HID, ln_b + (size_t)l * HID, h);
    }
    k_head_mfma<<<(N_NODES + 63) / 64, 256, 0, stream>>>(h, head_w1, head_b1,
                                                         head_w2, head_b2, out);
}

// Round 10
// 569.499 us; speedup vs baseline: 1.0644x; 1.0644x over previous
//
#include <hip/hip_runtime.h>

constexpr int N_NODES = 50000;
constexpr int N_EDGES = 800000;
constexpr int ND  = 32;
constexpr int ED  = 16;
constexpr int HID = 96;
constexpr int NLAYER = 3;

typedef unsigned short ushort_t;
typedef unsigned int uint_t;
typedef __attribute__((ext_vector_type(8))) short bf16x8;
typedef __attribute__((ext_vector_type(4))) float f32x4;

__device__ __forceinline__ float bf2f(ushort_t u) {
    union { float f; uint_t ui; } c; c.ui = ((uint_t)u) << 16; return c.f;
}
__device__ __forceinline__ ushort_t f2bf(float f) {
    uint_t u = __float_as_uint(f);
    return (ushort_t)((u + 0x7FFFu + ((u >> 16) & 1u)) >> 16);  // RNE
}

// ---------------- CSR build (by dst), once per call ----------------
// Single atomic pass: rank[e] = running count of dst[e]; cnt ends as degree.
__global__ void k_rank(const int* __restrict__ dst, int* __restrict__ cnt,
                       int* __restrict__ rank) {
    int e = blockIdx.x * 256 + threadIdx.x;
    if (e >= N_EDGES) return;
    rank[e] = atomicAdd(&cnt[dst[e]], 1);
}

__global__ void k_scan_block(const int* __restrict__ deg, int* __restrict__ rowptr,
                             int* __restrict__ bsum) {
    __shared__ int s[256];
    int i = blockIdx.x * 256 + threadIdx.x;
    int v = (i < N_NODES) ? deg[i] : 0;
    s[threadIdx.x] = v;
    __syncthreads();
    for (int off = 1; off < 256; off <<= 1) {
        int t = (threadIdx.x >= off) ? s[threadIdx.x - off] : 0;
        __syncthreads();
        s[threadIdx.x] += t;
        __syncthreads();
    }
    if (i < N_NODES) rowptr[i] = s[threadIdx.x] - v;
    if (threadIdx.x == 255) bsum[blockIdx.x] = s[255];
}

__global__ void k_scan_bsum(int* __restrict__ bsum, int nb) {
    __shared__ int s[256];
    int t = threadIdx.x;
    int v = (t < nb) ? bsum[t] : 0;
    s[t] = v;
    __syncthreads();
    for (int off = 1; off < 256; off <<= 1) {
        int tv = (t >= off) ? s[t - off] : 0;
        __syncthreads();
        s[t] += tv;
        __syncthreads();
    }
    if (t < nb) bsum[t] = s[t] - v;
}

__global__ void k_scan_add(int* __restrict__ rowptr, const int* __restrict__ bsum) {
    int i = blockIdx.x * 256 + threadIdx.x;
    if (i < N_NODES) rowptr[i] += bsum[blockIdx.x];
    if (i == 0) rowptr[N_NODES] = N_EDGES;
}

// ---- place: deterministic position, NO atomic — pure random 8B store ----
__global__ void k_place(const int* __restrict__ src, const int* __restrict__ dst,
                        const int* __restrict__ rank, const int* __restrict__ rowptr,
                        int2* __restrict__ csre) {
    int e = blockIdx.x * 256 + threadIdx.x;
    if (e >= N_EDGES) return;
    int p = rowptr[dst[e]] + rank[e];
    csre[p] = make_int2(src[e], e);
}

// ---- gather pass: random READS (L3-absorbed), sequential writes.
// Builds srcs/pdst/ea_csr in CSR order. ----
__global__ void k_gather(const int2* __restrict__ csre, const int* __restrict__ dstA,
                         const float* __restrict__ eattr, int* __restrict__ srcs,
                         int* __restrict__ pdst, ushort_t* __restrict__ ea) {
    int p = blockIdx.x * 256 + threadIdx.x;
    if (p >= N_EDGES) return;
    int2 se = csre[p];
    int e = se.y;
    srcs[p] = se.x;
    pdst[p] = dstA[e];
    const float4* er = (const float4*)(eattr + (size_t)e * ED);
    float4 v0 = er[0], v1 = er[1], v2 = er[2], v3 = er[3];
    uint4 w0, w1;
    w0.x = (uint_t)f2bf(v0.x) | ((uint_t)f2bf(v0.y) << 16);
    w0.y = (uint_t)f2bf(v0.z) | ((uint_t)f2bf(v0.w) << 16);
    w0.z = (uint_t)f2bf(v1.x) | ((uint_t)f2bf(v1.y) << 16);
    w0.w = (uint_t)f2bf(v1.z) | ((uint_t)f2bf(v1.w) << 16);
    w1.x = (uint_t)f2bf(v2.x) | ((uint_t)f2bf(v2.y) << 16);
    w1.y = (uint_t)f2bf(v2.z) | ((uint_t)f2bf(v2.w) << 16);
    w1.z = (uint_t)f2bf(v3.x) | ((uint_t)f2bf(v3.y) << 16);
    w1.w = (uint_t)f2bf(v3.z) | ((uint_t)f2bf(v3.w) << 16);
    uint4* ew = (uint4*)(ea + (size_t)p * ED);
    ew[0] = w0;
    ew[1] = w1;
}

// ---------------- proj: h = x @ proj_w + proj_b  (K=32) ----------------
__global__ __launch_bounds__(192) void k_proj(const float* __restrict__ x,
                                              const float* __restrict__ pw,
                                              const float* __restrict__ pb,
                                              float* __restrict__ h) {
    int t = threadIdx.x;
    int c = t % 96, half = t / 96;
    float wreg[ND];
#pragma unroll
    for (int k = 0; k < ND; k++) wreg[k] = pw[k * HID + c];
    float b = pb[c];
    int n0 = blockIdx.x * 16 + half * 8;
    for (int i = 0; i < 8; i += 2) {
        int na = n0 + i, nb = na + 1;
        const float4* xa = (const float4*)(x + (size_t)na * ND);
        const float4* xb = (const float4*)(x + (size_t)nb * ND);
        float accA = b, accB = b;
#pragma unroll
        for (int k4 = 0; k4 < ND / 4; k4++) {
            float4 va = xa[k4], vb = xb[k4];
            accA += va.x * wreg[4 * k4] + va.y * wreg[4 * k4 + 1] +
                    va.z * wreg[4 * k4 + 2] + va.w * wreg[4 * k4 + 3];
            accB += vb.x * wreg[4 * k4] + vb.y * wreg[4 * k4 + 1] +
                    vb.z * wreg[4 * k4 + 2] + vb.w * wreg[4 * k4 + 3];
        }
        h[(size_t)na * HID + c] = accA;
        h[(size_t)nb * HID + c] = accB;
    }
}

// ---- k_linlr_mfma: [xl|xr] = h @ [Wl|Wr] + [bl|br], bf16 out, MFMA ----
__global__ __launch_bounds__(256) void k_linlr_mfma(
    const float* __restrict__ h, const float* __restrict__ Wl,
    const float* __restrict__ bl, const float* __restrict__ Wr,
    const float* __restrict__ br, ushort_t* __restrict__ xl,
    ushort_t* __restrict__ xr) {
    __shared__ ushort_t sW[192 * 104];
    __shared__ float sB[192];
    int t = threadIdx.x;

    for (int idx = t; idx < 192 * 96; idx += 256) {
        int n = idx % 192, k = idx / 192;
        float v = (n < 96) ? Wl[k * 96 + n] : Wr[k * 96 + (n - 96)];
        sW[n * 104 + k] = f2bf(v);
    }
    if (t < 192) sB[t] = (t < 96) ? bl[t] : br[t - 96];
    __syncthreads();

    int wv = t >> 6, lane = t & 63;
    int m0 = blockIdx.x * 64 + wv * 16;
    if (m0 >= N_NODES) return;
    int m = lane & 15, quad = lane >> 4;

    bf16x8 afr[3];
    const float* hrow = h + (size_t)(m0 + m) * HID;
#pragma unroll
    for (int s = 0; s < 3; s++) {
        float4 v0 = *(const float4*)(hrow + s * 32 + quad * 8);
        float4 v1 = *(const float4*)(hrow + s * 32 + quad * 8 + 4);
        bf16x8 a;
        a[0] = (short)f2bf(v0.x); a[1] = (short)f2bf(v0.y);
        a[2] = (short)f2bf(v0.z); a[3] = (short)f2bf(v0.w);
        a[4] = (short)f2bf(v1.x); a[5] = (short)f2bf(v1.y);
        a[6] = (short)f2bf(v1.z); a[7] = (short)f2bf(v1.w);
        afr[s] = a;
    }

#pragma unroll
    for (int nt = 0; nt < 12; nt++) {
        int ch = nt * 16 + m;
        f32x4 acc = {0.f, 0.f, 0.f, 0.f};
#pragma unroll
        for (int s = 0; s < 3; s++) {
            bf16x8 bfr = *(const bf16x8*)(sW + (nt * 16 + m) * 104 + s * 32 + quad * 8);
            acc = __builtin_amdgcn_mfma_f32_16x16x32_bf16(afr[s], bfr, acc, 0, 0, 0);
        }
        float bias = sB[ch];
        ushort_t* dst = (ch < 96) ? (xl + (size_t)(m0 + quad * 4) * HID + ch)
                                  : (xr + (size_t)(m0 + quad * 4) * HID + (ch - 96));
#pragma unroll
        for (int r = 0; r < 4; r++)
            dst[(size_t)r * HID] = f2bf(acc[r] + bias);
    }
}

// ---- k_ev: edge-parallel attention weights via MFMA, CSR order, pipelined ----
__global__ __launch_bounds__(256) void k_ev(
    const ushort_t* __restrict__ xlb, const ushort_t* __restrict__ xrb,
    const ushort_t* __restrict__ ea, const int* __restrict__ srcs,
    const int* __restrict__ pdst, const float* __restrict__ WeL,
    const float* __restrict__ attL, float4* __restrict__ ev) {
    int wid = blockIdx.x * 4 + (threadIdx.x >> 6);
    int lane = threadIdx.x & 63;
    if (wid >= N_EDGES / 128) return;
    int col = lane & 15, quad = lane >> 4;
    int comp = col & 1, base = col >> 1;

    // preload this wave's 128 srcs/pdst values (2 per lane)
    int2 sp = *(const int2*)(srcs + wid * 128 + 2 * lane);
    int2 dp = *(const int2*)(pdst + wid * 128 + 2 * lane);

    // wave-invariant A fragments (We^T) and att values
    bf16x8 afr[6];
#pragma unroll
    for (int mc = 0; mc < 6; mc++) {
        bf16x8 a = {0, 0, 0, 0, 0, 0, 0, 0};
        if (quad < 2) {
#pragma unroll
            for (int j = 0; j < 8; j++)
                a[j] = (short)f2bf(WeL[(quad * 8 + j) * HID + mc * 16 + col]);
        }
        afr[mc] = a;
    }
    float attr[6][4];
#pragma unroll
    for (int mc = 0; mc < 6; mc++)
#pragma unroll
        for (int r = 0; r < 4; r++)
            attr[mc][r] = attL[mc * 16 + quad * 4 + r];

    // pipeline registers (2 batches in flight)
    bf16x8 bfr[2];
    uint2 xu[2][6], ru[2][6];

    auto getsd = [&](int b, int& sv, int& dv) {
        int sl = b * 8 + base;
        int sx = __shfl(sp.x, sl), sy = __shfl(sp.y, sl);
        int dx = __shfl(dp.x, sl), dy = __shfl(dp.y, sl);
        sv = comp ? sy : sx;
        dv = comp ? dy : dx;
    };
    auto issue = [&](int b, int pp) {
        int sv, dv;
        getsd(b, sv, dv);
        int p = wid * 128 + b * 16 + col;
        bf16x8 z8 = {0, 0, 0, 0, 0, 0, 0, 0};
        bfr[pp] = (quad < 2) ? *(const bf16x8*)(ea + (size_t)p * ED + quad * 8) : z8;
        const ushort_t* xp = xlb + (size_t)sv * HID + quad * 4;
        const ushort_t* rp = xrb + (size_t)dv * HID + quad * 4;
#pragma unroll
        for (int mc = 0; mc < 6; mc++) {
            xu[pp][mc] = *(const uint2*)(xp + mc * 16);
            ru[pp][mc] = *(const uint2*)(rp + mc * 16);
        }
    };

    issue(0, 0);
#pragma unroll
    for (int b = 0; b < 8; b++) {
        int pp = b & 1;
        if (b < 7) issue(b + 1, pp ^ 1);

        f32x4 zero4 = {0.f, 0.f, 0.f, 0.f};
        f32x4 d[6];
#pragma unroll
        for (int mc = 0; mc < 6; mc++)
            d[mc] = __builtin_amdgcn_mfma_f32_16x16x32_bf16(afr[mc], bfr[pp], zero4, 0, 0, 0);

        float s[6];
#pragma unroll
        for (int mc = 0; mc < 6; mc++) {
            uint2 a = xu[pp][mc], r = ru[pp][mc];
            float x0 = bf2f((ushort_t)(a.x & 0xffff)), x1 = bf2f((ushort_t)(a.x >> 16));
            float x2 = bf2f((ushort_t)(a.y & 0xffff)), x3 = bf2f((ushort_t)(a.y >> 16));
            float r0 = bf2f((ushort_t)(r.x & 0xffff)), r1 = bf2f((ushort_t)(r.x >> 16));
            float r2 = bf2f((ushort_t)(r.y & 0xffff)), r3 = bf2f((ushort_t)(r.y >> 16));
            float z0 = x0 + r0 + d[mc][0]; z0 = z0 > 0.f ? z0 : 0.2f * z0;
            float z1 = x1 + r1 + d[mc][1]; z1 = z1 > 0.f ? z1 : 0.2f * z1;
            float z2 = x2 + r2 + d[mc][2]; z2 = z2 > 0.f ? z2 : 0.2f * z2;
            float z3 = x3 + r3 + d[mc][3]; z3 = z3 > 0.f ? z3 : 0.2f * z3;
            s[mc] = z0 * attr[mc][0] + z1 * attr[mc][1] +
                    z2 * attr[mc][2] + z3 * attr[mc][3];
        }
        float U[6], V[6];
#pragma unroll
        for (int mc = 0; mc < 6; mc++) {
            U[mc] = s[mc] + __shfl_xor(s[mc], 16);
            V[mc] = U[mc] + __shfl_xor(U[mc], 32);
        }
        if (quad == 0) {
            float h0 = V[0] + U[1];
            float h1 = (V[1] - U[1]) + V[2];
            float h2 = V[3] + U[4];
            float h3 = (V[4] - U[4]) + V[5];
            int p = wid * 128 + b * 16 + col;
            ev[p] = make_float4(__expf(h0), __expf(h1), __expf(h2), __expf(h3));
        }
    }
}

// ---- k_agg: weighted sum + residual + LayerNorm (CSR order, ev sequential) ----
__global__ __launch_bounds__(256) void k_agg(
    const ushort_t* __restrict__ xlb, const float* __restrict__ evf,
    const int* __restrict__ srcs, const int* __restrict__ rowptr,
    const float* __restrict__ convb, const float* __restrict__ lng,
    const float* __restrict__ lnb, float* __restrict__ h) {
    int lane = threadIdx.x & 63;
    int node = blockIdx.x * 4 + (threadIdx.x >> 6);
    int slot = lane >> 4, q = lane & 15;
    int c0 = q * 6, head = q >> 2;
    int beg = rowptr[node], end = rowptr[node + 1];
    int cnt = (end - beg + 3) >> 2;

    float n0 = 0.f, n1 = 0.f, n2 = 0.f, n3 = 0.f, n4 = 0.f, n5 = 0.f, den = 0.f;
    if (cnt > 0) {
        int p = beg + slot;
        bool v = p < end;
        int pc = v ? p : beg;
        int src = srcs[pc];
        float evv = evf[4 * pc + head];
        const ushort_t* xp = xlb + (size_t)src * HID + c0;
        uint_t a0 = *(const uint_t*)(xp);
        uint_t a1 = *(const uint_t*)(xp + 2);
        uint_t a2 = *(const uint_t*)(xp + 4);
        for (int it = 0; it < cnt; ++it) {
            int pn = beg + (it + 1) * 4 + slot;
            bool vn = pn < end;
            int pcn = vn ? pn : beg;
            int srcn = srcs[pcn];
            float evn = evf[4 * pcn + head];
            const ushort_t* xpn = xlb + (size_t)srcn * HID + c0;
            uint_t b0 = *(const uint_t*)(xpn);
            uint_t b1 = *(const uint_t*)(xpn + 2);
            uint_t b2 = *(const uint_t*)(xpn + 4);

            float e = v ? evv : 0.f;
            n0 += e * bf2f((ushort_t)(a0 & 0xffff));
            n1 += e * bf2f((ushort_t)(a0 >> 16));
            n2 += e * bf2f((ushort_t)(a1 & 0xffff));
            n3 += e * bf2f((ushort_t)(a1 >> 16));
            n4 += e * bf2f((ushort_t)(a2 & 0xffff));
            n5 += e * bf2f((ushort_t)(a2 >> 16));
            den += e;

            v = vn; evv = evn; a0 = b0; a1 = b1; a2 = b2;
        }
    }
    n0 += __shfl_xor(n0, 16); n0 += __shfl_xor(n0, 32);
    n1 += __shfl_xor(n1, 16); n1 += __shfl_xor(n1, 32);
    n2 += __shfl_xor(n2, 16); n2 += __shfl_xor(n2, 32);
    n3 += __shfl_xor(n3, 16); n3 += __shfl_xor(n3, 32);
    n4 += __shfl_xor(n4, 16); n4 += __shfl_xor(n4, 32);
    n5 += __shfl_xor(n5, 16); n5 += __shfl_xor(n5, 32);
    den += __shfl_xor(den, 16); den += __shfl_xor(den, 32);

    size_t nb = (size_t)node * HID + c0;
    float inv = 1.f / (den + 1e-16f);
    float v0 = h[nb + 0] + n0 * inv + convb[c0 + 0];
    float v1 = h[nb + 1] + n1 * inv + convb[c0 + 1];
    float v2 = h[nb + 2] + n2 * inv + convb[c0 + 2];
    float v3 = h[nb + 3] + n3 * inv + convb[c0 + 3];
    float v4 = h[nb + 4] + n4 * inv + convb[c0 + 4];
    float v5 = h[nb + 5] + n5 * inv + convb[c0 + 5];
    float sm = v0 + v1 + v2 + v3 + v4 + v5;
    sm += __shfl_xor(sm, 1); sm += __shfl_xor(sm, 2);
    sm += __shfl_xor(sm, 4); sm += __shfl_xor(sm, 8);
    float mu = sm * (1.f / 96.f);
    float d0 = v0 - mu, d1 = v1 - mu, d2 = v2 - mu;
    float d3 = v3 - mu, d4 = v4 - mu, d5 = v5 - mu;
    float sv = d0 * d0 + d1 * d1 + d2 * d2 + d3 * d3 + d4 * d4 + d5 * d5;
    sv += __shfl_xor(sv, 1); sv += __shfl_xor(sv, 2);
    sv += __shfl_xor(sv, 4); sv += __shfl_xor(sv, 8);
    float rstd = rsqrtf(sv * (1.f / 96.f) + 1e-5f);
    if (slot == 0) {
        h[nb + 0] = d0 * rstd * lng[c0 + 0] + lnb[c0 + 0];
        h[nb + 1] = d1 * rstd * lng[c0 + 1] + lnb[c0 + 1];
        h[nb + 2] = d2 * rstd * lng[c0 + 2] + lnb[c0 + 2];
        h[nb + 3] = d3 * rstd * lng[c0 + 3] + lnb[c0 + 3];
        h[nb + 4] = d4 * rstd * lng[c0 + 4] + lnb[c0 + 4];
        h[nb + 5] = d5 * rstd * lng[c0 + 5] + lnb[c0 + 5];
    }
}

// ---- k_head_mfma: out = gelu(h@W1+b1)@W2+b2 via MFMA ----
__global__ __launch_bounds__(256) void k_head_mfma(
    const float* __restrict__ h, const float* __restrict__ W1,
    const float* __restrict__ b1, const float* __restrict__ W2,
    const float* __restrict__ b2, float* __restrict__ out) {
    __shared__ ushort_t sW[48 * 104];
    __shared__ float sB1[48];
    __shared__ float sW2[48];
    int t = threadIdx.x;
    for (int idx = t; idx < 48 * 96; idx += 256) {
        int j = idx % 48, k = idx / 48;
        sW[j * 104 + k] = f2bf(W1[k * 48 + j]);
    }
    if (t < 48) { sB1[t] = b1[t]; sW2[t] = W2[t]; }
    __syncthreads();

    int wv = t >> 6, lane = t & 63;
    int m0 = blockIdx.x * 64 + wv * 16;
    if (m0 >= N_NODES) return;
    int col = lane & 15, quad = lane >> 4;

    bf16x8 afr[3];
    const float* hrow = h + (size_t)(m0 + col) * HID;
#pragma unroll
    for (int s = 0; s < 3; s++) {
        float4 v0 = *(const float4*)(hrow + s * 32 + quad * 8);
        float4 v1 = *(const float4*)(hrow + s * 32 + quad * 8 + 4);
        bf16x8 a;
        a[0] = (short)f2bf(v0.x); a[1] = (short)f2bf(v0.y);
        a[2] = (short)f2bf(v0.z); a[3] = (short)f2bf(v0.w);
        a[4] = (short)f2bf(v1.x); a[5] = (short)f2bf(v1.y);
        a[6] = (short)f2bf(v1.z); a[7] = (short)f2bf(v1.w);
        afr[s] = a;
    }

    const float inv_sqrt2 = 0.70710678118654752f;
    float y0 = 0.f, y1 = 0.f, y2 = 0.f, y3 = 0.f;
#pragma unroll
    for (int nt = 0; nt < 3; nt++) {
        f32x4 acc = {0.f, 0.f, 0.f, 0.f};
#pragma unroll
        for (int s = 0; s < 3; s++) {
            bf16x8 bfr = *(const bf16x8*)(sW + (nt * 16 + col) * 104 + s * 32 + quad * 8);
            acc = __builtin_amdgcn_mfma_f32_16x16x32_bf16(afr[s], bfr, acc, 0, 0, 0);
        }
        int ch = nt * 16 + col;
        float bias = sB1[ch], w2 = sW2[ch];
        float v, g;
        v = acc[0] + bias; g = 0.5f * v * (1.f + erff(v * inv_sqrt2)); y0 += g * w2;
        v = acc[1] + bias; g = 0.5f * v * (1.f + erff(v * inv_sqrt2)); y1 += g * w2;
        v = acc[2] + bias; g = 0.5f * v * (1.f + erff(v * inv_sqrt2)); y2 += g * w2;
        v = acc[3] + bias; g = 0.5f * v * (1.f + erff(v * inv_sqrt2)); y3 += g * w2;
    }
    y0 += __shfl_xor(y0, 1); y0 += __shfl_xor(y0, 2);
    y0 += __shfl_xor(y0, 4); y0 += __shfl_xor(y0, 8);
    y1 += __shfl_xor(y1, 1); y1 += __shfl_xor(y1, 2);
    y1 += __shfl_xor(y1, 4); y1 += __shfl_xor(y1, 8);
    y2 += __shfl_xor(y2, 1); y2 += __shfl_xor(y2, 2);
    y2 += __shfl_xor(y2, 4); y2 += __shfl_xor(y2, 8);
    y3 += __shfl_xor(y3, 1); y3 += __shfl_xor(y3, 2);
    y3 += __shfl_xor(y3, 4); y3 += __shfl_xor(y3, 8);
    if (col == 0) {
        float bb = b2[0];
        out[m0 + quad * 4 + 0] = y0 + bb;
        out[m0 + quad * 4 + 1] = y1 + bb;
        out[m0 + quad * 4 + 2] = y2 + bb;
        out[m0 + quad * 4 + 3] = y3 + bb;
    }
}

extern "C" void kernel_launch(void* const* d_in, const int* in_sizes, int n_in,
                              void* d_out, int out_size, void* d_ws, size_t ws_size,
                              hipStream_t stream) {
    const float* x       = (const float*)d_in[0];
    const int*   eidx    = (const int*)  d_in[1];
    const float* eattr   = (const float*)d_in[2];
    const float* proj_w  = (const float*)d_in[3];
    const float* proj_b  = (const float*)d_in[4];
    const float* lin_l_w = (const float*)d_in[5];
    const float* lin_l_b = (const float*)d_in[6];
    const float* lin_r_w = (const float*)d_in[7];
    const float* lin_r_b = (const float*)d_in[8];
    const float* lin_e_w = (const float*)d_in[9];
    const float* att     = (const float*)d_in[10];
    const float* conv_b  = (const float*)d_in[11];
    const float* ln_g    = (const float*)d_in[12];
    const float* ln_b    = (const float*)d_in[13];
    const float* head_w1 = (const float*)d_in[14];
    const float* head_b1 = (const float*)d_in[15];
    const float* head_w2 = (const float*)d_in[16];
    const float* head_b2 = (const float*)d_in[17];
    float* out = (float*)d_out;

    char* p = (char*)d_ws;
    auto alloc = [&](size_t bytes) -> char* {
        char* r = p;
        p += (bytes + 255) & ~size_t(255);
        return r;
    };
    float*    h      = (float*)alloc(sizeof(float) * (size_t)N_NODES * HID);
    ushort_t* xl     = (ushort_t*)alloc(2 * (size_t)N_NODES * HID);
    ushort_t* xr     = (ushort_t*)alloc(2 * (size_t)N_NODES * HID);
    int*      cnt    = (int*)alloc(4 * (size_t)N_NODES);
    int*      rank   = (int*)alloc(4 * (size_t)N_EDGES);
    int*      rowptr = (int*)alloc(4 * (size_t)(N_NODES + 1));
    int*      bsum   = (int*)alloc(4 * 256);
    int2*     csre   = (int2*)alloc(8 * (size_t)N_EDGES);
    int*      srcs   = (int*)alloc(4 * ((size_t)N_EDGES + 256));
    int*      pdst   = (int*)alloc(4 * ((size_t)N_EDGES + 256));
    ushort_t* ea_csr = (ushort_t*)alloc(2 * (size_t)N_EDGES * ED);
    float4*   ev     = (float4*)alloc(16 * (size_t)N_EDGES);

    const int* srcA = eidx;
    const int* dstA = eidx + N_EDGES;

    int ebl = (N_EDGES + 255) / 256;   // 3125
    int nbl = (N_NODES + 255) / 256;   // 196

    hipMemsetAsync(cnt, 0, 4 * (size_t)N_NODES, stream);
    k_rank<<<ebl, 256, 0, stream>>>(dstA, cnt, rank);
    k_scan_block<<<nbl, 256, 0, stream>>>(cnt, rowptr, bsum);
    k_scan_bsum<<<1, 256, 0, stream>>>(bsum, nbl);
    k_scan_add<<<nbl, 256, 0, stream>>>(rowptr, bsum);
    k_place<<<ebl, 256, 0, stream>>>(srcA, dstA, rank, rowptr, csre);
    k_gather<<<ebl, 256, 0, stream>>>(csre, dstA, eattr, srcs, pdst, ea_csr);

    k_proj<<<N_NODES / 16, 192, 0, stream>>>(x, proj_w, proj_b, h);
    for (int l = 0; l < NLAYER; l++) {
        k_linlr_mfma<<<(N_NODES + 63) / 64, 256, 0, stream>>>(
            h, lin_l_w + (size_t)l * HID * HID, lin_l_b + (size_t)l * HID,
            lin_r_w + (size_t)l * HID * HID, lin_r_b + (size_t)l * HID, xl, xr);
        k_ev<<<1563, 256, 0, stream>>>(xl, xr, ea_csr, srcs, pdst,
                                       lin_e_w + (size_t)l * ED * HID,
                                       att + (size_t)l * HID,
                                       (float4*)ev);
        k_agg<<<N_NODES / 4, 256, 0, stream>>>(
            xl, (const float*)ev, srcs, rowptr, conv_b + (size_t)l * HID,
            ln_g + (size_t)l * HID, ln_b + (size_t)l * HID, h);
    }
    k_head_mfma<<<(N_NODES + 63) / 64, 256, 0, stream>>>(h, head_w1, head_b1,
                                                         head_w2, head_b2, out);
}

// Round 11
// 564.026 us; speedup vs baseline: 1.0748x; 1.0097x over previous
//
#include <hip/hip_runtime.h>

constexpr int N_NODES = 50000;
constexpr int N_EDGES = 800000;
constexpr int ND  = 32;
constexpr int ED  = 16;
constexpr int HID = 96;
constexpr int NLAYER = 3;

typedef unsigned short ushort_t;
typedef unsigned int uint_t;
typedef __attribute__((ext_vector_type(8))) short bf16x8;
typedef __attribute__((ext_vector_type(4))) float f32x4;

__device__ __forceinline__ float bf2f(ushort_t u) {
    union { float f; uint_t ui; } c; c.ui = ((uint_t)u) << 16; return c.f;
}
__device__ __forceinline__ ushort_t f2bf(float f) {
    uint_t u = __float_as_uint(f);
    return (ushort_t)((u + 0x7FFFu + ((u >> 16) & 1u)) >> 16);  // RNE
}

// ---------------- CSR build (by dst), once per call ----------------
// Single atomic pass: rank[e] = running count of dst[e]; cnt ends as degree.
__global__ void k_rank(const int* __restrict__ dst, int* __restrict__ cnt,
                       int* __restrict__ rank) {
    int e = blockIdx.x * 256 + threadIdx.x;
    if (e >= N_EDGES) return;
    rank[e] = atomicAdd(&cnt[dst[e]], 1);
}

__global__ void k_scan_block(const int* __restrict__ deg, int* __restrict__ rowptr,
                             int* __restrict__ bsum) {
    __shared__ int s[256];
    int i = blockIdx.x * 256 + threadIdx.x;
    int v = (i < N_NODES) ? deg[i] : 0;
    s[threadIdx.x] = v;
    __syncthreads();
    for (int off = 1; off < 256; off <<= 1) {
        int t = (threadIdx.x >= off) ? s[threadIdx.x - off] : 0;
        __syncthreads();
        s[threadIdx.x] += t;
        __syncthreads();
    }
    if (i < N_NODES) rowptr[i] = s[threadIdx.x] - v;
    if (threadIdx.x == 255) bsum[blockIdx.x] = s[255];
}

__global__ void k_scan_bsum(int* __restrict__ bsum, int nb) {
    __shared__ int s[256];
    int t = threadIdx.x;
    int v = (t < nb) ? bsum[t] : 0;
    s[t] = v;
    __syncthreads();
    for (int off = 1; off < 256; off <<= 1) {
        int tv = (t >= off) ? s[t - off] : 0;
        __syncthreads();
        s[t] += tv;
        __syncthreads();
    }
    if (t < nb) bsum[t] = s[t] - v;
}

__global__ void k_scan_add(int* __restrict__ rowptr, const int* __restrict__ bsum) {
    int i = blockIdx.x * 256 + threadIdx.x;
    if (i < N_NODES) rowptr[i] += bsum[blockIdx.x];
    if (i == 0) rowptr[N_NODES] = N_EDGES;
}

// ---- place: deterministic position, NO atomic — pure random 8B store ----
__global__ void k_place(const int* __restrict__ src, const int* __restrict__ dst,
                        const int* __restrict__ rank, const int* __restrict__ rowptr,
                        int2* __restrict__ csre) {
    int e = blockIdx.x * 256 + threadIdx.x;
    if (e >= N_EDGES) return;
    int p = rowptr[dst[e]] + rank[e];
    csre[p] = make_int2(src[e], e);
}

// ---- gather pass: random READS (L3-absorbed), sequential writes. ----
__global__ void k_gather(const int2* __restrict__ csre, const int* __restrict__ dstA,
                         const float* __restrict__ eattr, int* __restrict__ srcs,
                         int* __restrict__ pdst, ushort_t* __restrict__ ea) {
    int p = blockIdx.x * 256 + threadIdx.x;
    if (p >= N_EDGES) return;
    int2 se = csre[p];
    int e = se.y;
    srcs[p] = se.x;
    pdst[p] = dstA[e];
    const float4* er = (const float4*)(eattr + (size_t)e * ED);
    float4 v0 = er[0], v1 = er[1], v2 = er[2], v3 = er[3];
    uint4 w0, w1;
    w0.x = (uint_t)f2bf(v0.x) | ((uint_t)f2bf(v0.y) << 16);
    w0.y = (uint_t)f2bf(v0.z) | ((uint_t)f2bf(v0.w) << 16);
    w0.z = (uint_t)f2bf(v1.x) | ((uint_t)f2bf(v1.y) << 16);
    w0.w = (uint_t)f2bf(v1.z) | ((uint_t)f2bf(v1.w) << 16);
    w1.x = (uint_t)f2bf(v2.x) | ((uint_t)f2bf(v2.y) << 16);
    w1.y = (uint_t)f2bf(v2.z) | ((uint_t)f2bf(v2.w) << 16);
    w1.z = (uint_t)f2bf(v3.x) | ((uint_t)f2bf(v3.y) << 16);
    w1.w = (uint_t)f2bf(v3.z) | ((uint_t)f2bf(v3.w) << 16);
    uint4* ew = (uint4*)(ea + (size_t)p * ED);
    ew[0] = w0;
    ew[1] = w1;
}

// ---------------- proj: h = x @ proj_w + proj_b  (K=32) ----------------
__global__ __launch_bounds__(192) void k_proj(const float* __restrict__ x,
                                              const float* __restrict__ pw,
                                              const float* __restrict__ pb,
                                              float* __restrict__ h) {
    int t = threadIdx.x;
    int c = t % 96, half = t / 96;
    float wreg[ND];
#pragma unroll
    for (int k = 0; k < ND; k++) wreg[k] = pw[k * HID + c];
    float b = pb[c];
    int n0 = blockIdx.x * 16 + half * 8;
    for (int i = 0; i < 8; i += 2) {
        int na = n0 + i, nb = na + 1;
        const float4* xa = (const float4*)(x + (size_t)na * ND);
        const float4* xb = (const float4*)(x + (size_t)nb * ND);
        float accA = b, accB = b;
#pragma unroll
        for (int k4 = 0; k4 < ND / 4; k4++) {
            float4 va = xa[k4], vb = xb[k4];
            accA += va.x * wreg[4 * k4] + va.y * wreg[4 * k4 + 1] +
                    va.z * wreg[4 * k4 + 2] + va.w * wreg[4 * k4 + 3];
            accB += vb.x * wreg[4 * k4] + vb.y * wreg[4 * k4 + 1] +
                    vb.z * wreg[4 * k4 + 2] + vb.w * wreg[4 * k4 + 3];
        }
        h[(size_t)na * HID + c] = accA;
        h[(size_t)nb * HID + c] = accB;
    }
}

// ---- k_linlr_mfma: [xl|xr] = h @ [Wl|Wr] + [bl|br], bf16 out, MFMA ----
__global__ __launch_bounds__(256) void k_linlr_mfma(
    const float* __restrict__ h, const float* __restrict__ Wl,
    const float* __restrict__ bl, const float* __restrict__ Wr,
    const float* __restrict__ br, ushort_t* __restrict__ xl,
    ushort_t* __restrict__ xr) {
    __shared__ ushort_t sW[192 * 104];
    __shared__ float sB[192];
    int t = threadIdx.x;

    for (int idx = t; idx < 192 * 96; idx += 256) {
        int n = idx % 192, k = idx / 192;
        float v = (n < 96) ? Wl[k * 96 + n] : Wr[k * 96 + (n - 96)];
        sW[n * 104 + k] = f2bf(v);
    }
    if (t < 192) sB[t] = (t < 96) ? bl[t] : br[t - 96];
    __syncthreads();

    int wv = t >> 6, lane = t & 63;
    int m0 = blockIdx.x * 64 + wv * 16;
    if (m0 >= N_NODES) return;
    int m = lane & 15, quad = lane >> 4;

    bf16x8 afr[3];
    const float* hrow = h + (size_t)(m0 + m) * HID;
#pragma unroll
    for (int s = 0; s < 3; s++) {
        float4 v0 = *(const float4*)(hrow + s * 32 + quad * 8);
        float4 v1 = *(const float4*)(hrow + s * 32 + quad * 8 + 4);
        bf16x8 a;
        a[0] = (short)f2bf(v0.x); a[1] = (short)f2bf(v0.y);
        a[2] = (short)f2bf(v0.z); a[3] = (short)f2bf(v0.w);
        a[4] = (short)f2bf(v1.x); a[5] = (short)f2bf(v1.y);
        a[6] = (short)f2bf(v1.z); a[7] = (short)f2bf(v1.w);
        afr[s] = a;
    }

#pragma unroll
    for (int nt = 0; nt < 12; nt++) {
        int ch = nt * 16 + m;
        f32x4 acc = {0.f, 0.f, 0.f, 0.f};
#pragma unroll
        for (int s = 0; s < 3; s++) {
            bf16x8 bfr = *(const bf16x8*)(sW + (nt * 16 + m) * 104 + s * 32 + quad * 8);
            acc = __builtin_amdgcn_mfma_f32_16x16x32_bf16(afr[s], bfr, acc, 0, 0, 0);
        }
        float bias = sB[ch];
        ushort_t* dst = (ch < 96) ? (xl + (size_t)(m0 + quad * 4) * HID + ch)
                                  : (xr + (size_t)(m0 + quad * 4) * HID + (ch - 96));
#pragma unroll
        for (int r = 0; r < 4; r++)
            dst[(size_t)r * HID] = f2bf(acc[r] + bias);
    }
}

// ---- k_ev: edge-parallel attention weights via MFMA, CSR order, pipelined ----
__global__ __launch_bounds__(256) void k_ev(
    const ushort_t* __restrict__ xlb, const ushort_t* __restrict__ xrb,
    const ushort_t* __restrict__ ea, const int* __restrict__ srcs,
    const int* __restrict__ pdst, const float* __restrict__ WeL,
    const float* __restrict__ attL, float4* __restrict__ ev) {
    int wid = blockIdx.x * 4 + (threadIdx.x >> 6);
    int lane = threadIdx.x & 63;
    if (wid >= N_EDGES / 128) return;
    int col = lane & 15, quad = lane >> 4;
    int comp = col & 1, base = col >> 1;

    int2 sp = *(const int2*)(srcs + wid * 128 + 2 * lane);
    int2 dp = *(const int2*)(pdst + wid * 128 + 2 * lane);

    bf16x8 afr[6];
#pragma unroll
    for (int mc = 0; mc < 6; mc++) {
        bf16x8 a = {0, 0, 0, 0, 0, 0, 0, 0};
        if (quad < 2) {
#pragma unroll
            for (int j = 0; j < 8; j++)
                a[j] = (short)f2bf(WeL[(quad * 8 + j) * HID + mc * 16 + col]);
        }
        afr[mc] = a;
    }
    float attr[6][4];
#pragma unroll
    for (int mc = 0; mc < 6; mc++)
#pragma unroll
        for (int r = 0; r < 4; r++)
            attr[mc][r] = attL[mc * 16 + quad * 4 + r];

    bf16x8 bfr[2];
    uint2 xu[2][6], ru[2][6];

    auto getsd = [&](int b, int& sv, int& dv) {
        int sl = b * 8 + base;
        int sx = __shfl(sp.x, sl), sy = __shfl(sp.y, sl);
        int dx = __shfl(dp.x, sl), dy = __shfl(dp.y, sl);
        sv = comp ? sy : sx;
        dv = comp ? dy : dx;
    };
    auto issue = [&](int b, int pp) {
        int sv, dv;
        getsd(b, sv, dv);
        int p = wid * 128 + b * 16 + col;
        bf16x8 z8 = {0, 0, 0, 0, 0, 0, 0, 0};
        bfr[pp] = (quad < 2) ? *(const bf16x8*)(ea + (size_t)p * ED + quad * 8) : z8;
        const ushort_t* xp = xlb + (size_t)sv * HID + quad * 4;
        const ushort_t* rp = xrb + (size_t)dv * HID + quad * 4;
#pragma unroll
        for (int mc = 0; mc < 6; mc++) {
            xu[pp][mc] = *(const uint2*)(xp + mc * 16);
            ru[pp][mc] = *(const uint2*)(rp + mc * 16);
        }
    };

    issue(0, 0);
#pragma unroll
    for (int b = 0; b < 8; b++) {
        int pp = b & 1;
        if (b < 7) issue(b + 1, pp ^ 1);

        f32x4 zero4 = {0.f, 0.f, 0.f, 0.f};
        f32x4 d[6];
#pragma unroll
        for (int mc = 0; mc < 6; mc++)
            d[mc] = __builtin_amdgcn_mfma_f32_16x16x32_bf16(afr[mc], bfr[pp], zero4, 0, 0, 0);

        float s[6];
#pragma unroll
        for (int mc = 0; mc < 6; mc++) {
            uint2 a = xu[pp][mc], r = ru[pp][mc];
            float x0 = bf2f((ushort_t)(a.x & 0xffff)), x1 = bf2f((ushort_t)(a.x >> 16));
            float x2 = bf2f((ushort_t)(a.y & 0xffff)), x3 = bf2f((ushort_t)(a.y >> 16));
            float r0 = bf2f((ushort_t)(r.x & 0xffff)), r1 = bf2f((ushort_t)(r.x >> 16));
            float r2 = bf2f((ushort_t)(r.y & 0xffff)), r3 = bf2f((ushort_t)(r.y >> 16));
            float z0 = x0 + r0 + d[mc][0]; z0 = z0 > 0.f ? z0 : 0.2f * z0;
            float z1 = x1 + r1 + d[mc][1]; z1 = z1 > 0.f ? z1 : 0.2f * z1;
            float z2 = x2 + r2 + d[mc][2]; z2 = z2 > 0.f ? z2 : 0.2f * z2;
            float z3 = x3 + r3 + d[mc][3]; z3 = z3 > 0.f ? z3 : 0.2f * z3;
            s[mc] = z0 * attr[mc][0] + z1 * attr[mc][1] +
                    z2 * attr[mc][2] + z3 * attr[mc][3];
        }
        float U[6], V[6];
#pragma unroll
        for (int mc = 0; mc < 6; mc++) {
            U[mc] = s[mc] + __shfl_xor(s[mc], 16);
            V[mc] = U[mc] + __shfl_xor(U[mc], 32);
        }
        if (quad == 0) {
            float h0 = V[0] + U[1];
            float h1 = (V[1] - U[1]) + V[2];
            float h2 = V[3] + U[4];
            float h3 = (V[4] - U[4]) + V[5];
            int p = wid * 128 + b * 16 + col;
            ev[p] = make_float4(__expf(h0), __expf(h1), __expf(h2), __expf(h3));
        }
    }
}

// ---- k_agg: weighted sum + residual + LayerNorm. 8 edge-slots x 8 lanes
// (12 ch/lane) -> serial gather depth = deg/8 (~2), 2-stage pipeline. ----
__global__ __launch_bounds__(256) void k_agg(
    const ushort_t* __restrict__ xlb, const float* __restrict__ evf,
    const int* __restrict__ srcs, const int* __restrict__ rowptr,
    const float* __restrict__ convb, const float* __restrict__ lng,
    const float* __restrict__ lnb, float* __restrict__ h) {
    int lane = threadIdx.x & 63;
    int node = blockIdx.x * 4 + (threadIdx.x >> 6);
    int slot = lane >> 3, q = lane & 7;      // 8 slots x 8 channel-lanes
    int c0 = q * 12, head = q >> 1;          // 12 ch/lane; head = c0/24
    int beg = rowptr[node], end = rowptr[node + 1];
    int cnt = (end - beg + 7) >> 3;

    float n[12];
#pragma unroll
    for (int j = 0; j < 12; j++) n[j] = 0.f;
    float den = 0.f;

    if (cnt > 0) {
        int p = beg + slot;
        bool v = p < end;
        int pc = v ? p : beg;
        int src = srcs[pc];
        float evv = evf[4 * pc + head];
        const ushort_t* xp = xlb + (size_t)src * HID + c0;
        uint_t a0 = *(const uint_t*)(xp);
        uint_t a1 = *(const uint_t*)(xp + 2);
        uint_t a2 = *(const uint_t*)(xp + 4);
        uint_t a3 = *(const uint_t*)(xp + 6);
        uint_t a4 = *(const uint_t*)(xp + 8);
        uint_t a5 = *(const uint_t*)(xp + 10);
        for (int it = 0; it < cnt; ++it) {
            int pn = beg + (it + 1) * 8 + slot;
            bool vn = pn < end;
            int pcn = vn ? pn : beg;
            int srcn = srcs[pcn];
            float evn = evf[4 * pcn + head];
            const ushort_t* xpn = xlb + (size_t)srcn * HID + c0;
            uint_t b0 = *(const uint_t*)(xpn);
            uint_t b1 = *(const uint_t*)(xpn + 2);
            uint_t b2 = *(const uint_t*)(xpn + 4);
            uint_t b3 = *(const uint_t*)(xpn + 6);
            uint_t b4 = *(const uint_t*)(xpn + 8);
            uint_t b5 = *(const uint_t*)(xpn + 10);

            float e = v ? evv : 0.f;
            n[0]  += e * bf2f((ushort_t)(a0 & 0xffff));
            n[1]  += e * bf2f((ushort_t)(a0 >> 16));
            n[2]  += e * bf2f((ushort_t)(a1 & 0xffff));
            n[3]  += e * bf2f((ushort_t)(a1 >> 16));
            n[4]  += e * bf2f((ushort_t)(a2 & 0xffff));
            n[5]  += e * bf2f((ushort_t)(a2 >> 16));
            n[6]  += e * bf2f((ushort_t)(a3 & 0xffff));
            n[7]  += e * bf2f((ushort_t)(a3 >> 16));
            n[8]  += e * bf2f((ushort_t)(a4 & 0xffff));
            n[9]  += e * bf2f((ushort_t)(a4 >> 16));
            n[10] += e * bf2f((ushort_t)(a5 & 0xffff));
            n[11] += e * bf2f((ushort_t)(a5 >> 16));
            den += e;

            v = vn; evv = evn;
            a0 = b0; a1 = b1; a2 = b2; a3 = b3; a4 = b4; a5 = b5;
        }
    }
    // combine 8 slots
#pragma unroll
    for (int j = 0; j < 12; j++) {
        n[j] += __shfl_xor(n[j], 8);
        n[j] += __shfl_xor(n[j], 16);
        n[j] += __shfl_xor(n[j], 32);
    }
    den += __shfl_xor(den, 8);
    den += __shfl_xor(den, 16);
    den += __shfl_xor(den, 32);

    size_t nb = (size_t)node * HID + c0;
    float inv = 1.f / (den + 1e-16f);
    float4 h0 = *(const float4*)(h + nb);
    float4 h1 = *(const float4*)(h + nb + 4);
    float4 h2 = *(const float4*)(h + nb + 8);
    float vv[12] = {h0.x, h0.y, h0.z, h0.w, h1.x, h1.y, h1.z, h1.w,
                    h2.x, h2.y, h2.z, h2.w};
    float sm = 0.f;
#pragma unroll
    for (int j = 0; j < 12; j++) {
        vv[j] += n[j] * inv + convb[c0 + j];
        sm += vv[j];
    }
    sm += __shfl_xor(sm, 1); sm += __shfl_xor(sm, 2); sm += __shfl_xor(sm, 4);
    float mu = sm * (1.f / 96.f);
    float sv = 0.f;
#pragma unroll
    for (int j = 0; j < 12; j++) {
        vv[j] -= mu;
        sv += vv[j] * vv[j];
    }
    sv += __shfl_xor(sv, 1); sv += __shfl_xor(sv, 2); sv += __shfl_xor(sv, 4);
    float rstd = rsqrtf(sv * (1.f / 96.f) + 1e-5f);
    if (slot == 0) {
        float o[12];
#pragma unroll
        for (int j = 0; j < 12; j++)
            o[j] = vv[j] * rstd * lng[c0 + j] + lnb[c0 + j];
        *(float4*)(h + nb)     = make_float4(o[0], o[1], o[2], o[3]);
        *(float4*)(h + nb + 4) = make_float4(o[4], o[5], o[6], o[7]);
        *(float4*)(h + nb + 8) = make_float4(o[8], o[9], o[10], o[11]);
    }
}

// ---- k_head_mfma: out = gelu(h@W1+b1)@W2+b2 via MFMA ----
__global__ __launch_bounds__(256) void k_head_mfma(
    const float* __restrict__ h, const float* __restrict__ W1,
    const float* __restrict__ b1, const float* __restrict__ W2,
    const float* __restrict__ b2, float* __restrict__ out) {
    __shared__ ushort_t sW[48 * 104];
    __shared__ float sB1[48];
    __shared__ float sW2[48];
    int t = threadIdx.x;
    for (int idx = t; idx < 48 * 96; idx += 256) {
        int j = idx % 48, k = idx / 48;
        sW[j * 104 + k] = f2bf(W1[k * 48 + j]);
    }
    if (t < 48) { sB1[t] = b1[t]; sW2[t] = W2[t]; }
    __syncthreads();

    int wv = t >> 6, lane = t & 63;
    int m0 = blockIdx.x * 64 + wv * 16;
    if (m0 >= N_NODES) return;
    int col = lane & 15, quad = lane >> 4;

    bf16x8 afr[3];
    const float* hrow = h + (size_t)(m0 + col) * HID;
#pragma unroll
    for (int s = 0; s < 3; s++) {
        float4 v0 = *(const float4*)(hrow + s * 32 + quad * 8);
        float4 v1 = *(const float4*)(hrow + s * 32 + quad * 8 + 4);
        bf16x8 a;
        a[0] = (short)f2bf(v0.x); a[1] = (short)f2bf(v0.y);
        a[2] = (short)f2bf(v0.z); a[3] = (short)f2bf(v0.w);
        a[4] = (short)f2bf(v1.x); a[5] = (short)f2bf(v1.y);
        a[6] = (short)f2bf(v1.z); a[7] = (short)f2bf(v1.w);
        afr[s] = a;
    }

    const float inv_sqrt2 = 0.70710678118654752f;
    float y0 = 0.f, y1 = 0.f, y2 = 0.f, y3 = 0.f;
#pragma unroll
    for (int nt = 0; nt < 3; nt++) {
        f32x4 acc = {0.f, 0.f, 0.f, 0.f};
#pragma unroll
        for (int s = 0; s < 3; s++) {
            bf16x8 bfr = *(const bf16x8*)(sW + (nt * 16 + col) * 104 + s * 32 + quad * 8);
            acc = __builtin_amdgcn_mfma_f32_16x16x32_bf16(afr[s], bfr, acc, 0, 0, 0);
        }
        int ch = nt * 16 + col;
        float bias = sB1[ch], w2 = sW2[ch];
        float v, g;
        v = acc[0] + bias; g = 0.5f * v * (1.f + erff(v * inv_sqrt2)); y0 += g * w2;
        v = acc[1] + bias; g = 0.5f * v * (1.f + erff(v * inv_sqrt2)); y1 += g * w2;
        v = acc[2] + bias; g = 0.5f * v * (1.f + erff(v * inv_sqrt2)); y2 += g * w2;
        v = acc[3] + bias; g = 0.5f * v * (1.f + erff(v * inv_sqrt2)); y3 += g * w2;
    }
    y0 += __shfl_xor(y0, 1); y0 += __shfl_xor(y0, 2);
    y0 += __shfl_xor(y0, 4); y0 += __shfl_xor(y0, 8);
    y1 += __shfl_xor(y1, 1); y1 += __shfl_xor(y1, 2);
    y1 += __shfl_xor(y1, 4); y1 += __shfl_xor(y1, 8);
    y2 += __shfl_xor(y2, 1); y2 += __shfl_xor(y2, 2);
    y2 += __shfl_xor(y2, 4); y2 += __shfl_xor(y2, 8);
    y3 += __shfl_xor(y3, 1); y3 += __shfl_xor(y3, 2);
    y3 += __shfl_xor(y3, 4); y3 += __shfl_xor(y3, 8);
    if (col == 0) {
        float bb = b2[0];
        out[m0 + quad * 4 + 0] = y0 + bb;
        out[m0 + quad * 4 + 1] = y1 + bb;
        out[m0 + quad * 4 + 2] = y2 + bb;
        out[m0 + quad * 4 + 3] = y3 + bb;
    }
}

extern "C" void kernel_launch(void* const* d_in, const int* in_sizes, int n_in,
                              void* d_out, int out_size, void* d_ws, size_t ws_size,
                              hipStream_t stream) {
    const float* x       = (const float*)d_in[0];
    const int*   eidx    = (const int*)  d_in[1];
    const float* eattr   = (const float*)d_in[2];
    const float* proj_w  = (const float*)d_in[3];
    const float* proj_b  = (const float*)d_in[4];
    const float* lin_l_w = (const float*)d_in[5];
    const float* lin_l_b = (const float*)d_in[6];
    const float* lin_r_w = (const float*)d_in[7];
    const float* lin_r_b = (const float*)d_in[8];
    const float* lin_e_w = (const float*)d_in[9];
    const float* att     = (const float*)d_in[10];
    const float* conv_b  = (const float*)d_in[11];
    const float* ln_g    = (const float*)d_in[12];
    const float* ln_b    = (const float*)d_in[13];
    const float* head_w1 = (const float*)d_in[14];
    const float* head_b1 = (const float*)d_in[15];
    const float* head_w2 = (const float*)d_in[16];
    const float* head_b2 = (const float*)d_in[17];
    float* out = (float*)d_out;

    char* p = (char*)d_ws;
    auto alloc = [&](size_t bytes) -> char* {
        char* r = p;
        p += (bytes + 255) & ~size_t(255);
        return r;
    };
    float*    h      = (float*)alloc(sizeof(float) * (size_t)N_NODES * HID);
    ushort_t* xl     = (ushort_t*)alloc(2 * (size_t)N_NODES * HID);
    ushort_t* xr     = (ushort_t*)alloc(2 * (size_t)N_NODES * HID);
    int*      cnt    = (int*)alloc(4 * (size_t)N_NODES);
    int*      rank   = (int*)alloc(4 * (size_t)N_EDGES);
    int*      rowptr = (int*)alloc(4 * (size_t)(N_NODES + 1));
    int*      bsum   = (int*)alloc(4 * 256);
    int2*     csre   = (int2*)alloc(8 * (size_t)N_EDGES);
    int*      srcs   = (int*)alloc(4 * ((size_t)N_EDGES + 256));
    int*      pdst   = (int*)alloc(4 * ((size_t)N_EDGES + 256));
    ushort_t* ea_csr = (ushort_t*)alloc(2 * (size_t)N_EDGES * ED);
    float4*   ev     = (float4*)alloc(16 * (size_t)N_EDGES);

    const int* srcA = eidx;
    const int* dstA = eidx + N_EDGES;

    int ebl = (N_EDGES + 255) / 256;   // 3125
    int nbl = (N_NODES + 255) / 256;   // 196

    hipMemsetAsync(cnt, 0, 4 * (size_t)N_NODES, stream);
    k_rank<<<ebl, 256, 0, stream>>>(dstA, cnt, rank);
    k_scan_block<<<nbl, 256, 0, stream>>>(cnt, rowptr, bsum);
    k_scan_bsum<<<1, 256, 0, stream>>>(bsum, nbl);
    k_scan_add<<<nbl, 256, 0, stream>>>(rowptr, bsum);
    k_place<<<ebl, 256, 0, stream>>>(srcA, dstA, rank, rowptr, csre);
    k_gather<<<ebl, 256, 0, stream>>>(csre, dstA, eattr, srcs, pdst, ea_csr);

    k_proj<<<N_NODES / 16, 192, 0, stream>>>(x, proj_w, proj_b, h);
    for (int l = 0; l < NLAYER; l++) {
        k_linlr_mfma<<<(N_NODES + 63) / 64, 256, 0, stream>>>(
            h, lin_l_w + (size_t)l * HID * HID, lin_l_b + (size_t)l * HID,
            lin_r_w + (size_t)l * HID * HID, lin_r_b + (size_t)l * HID, xl, xr);
        k_ev<<<1563, 256, 0, stream>>>(xl, xr, ea_csr, srcs, pdst,
                                       lin_e_w + (size_t)l * ED * HID,
                                       att + (size_t)l * HID,
                                       (float4*)ev);
        k_agg<<<N_NODES / 4, 256, 0, stream>>>(
            xl, (const float*)ev, srcs, rowptr, conv_b + (size_t)l * HID,
            ln_g + (size_t)l * HID, ln_b + (size_t)l * HID, h);
    }
    k_head_mfma<<<(N_NODES + 63) / 64, 256, 0, stream>>>(h, head_w1, head_b1,
                                                         head_w2, head_b2, out);
}

// Round 12
// 539.928 us; speedup vs baseline: 1.1227x; 1.0446x over previous
//
#include <hip/hip_runtime.h>

constexpr int N_NODES = 50000;
constexpr int N_EDGES = 800000;
constexpr int ND  = 32;
constexpr int ED  = 16;
constexpr int HID = 96;
constexpr int NLAYER = 3;

typedef unsigned short ushort_t;
typedef unsigned int uint_t;
typedef __attribute__((ext_vector_type(8))) short bf16x8;
typedef __attribute__((ext_vector_type(4))) float f32x4;

__device__ __forceinline__ float bf2f(ushort_t u) {
    union { float f; uint_t ui; } c; c.ui = ((uint_t)u) << 16; return c.f;
}
__device__ __forceinline__ ushort_t f2bf(float f) {
    uint_t u = __float_as_uint(f);
    return (ushort_t)((u + 0x7FFFu + ((u >> 16) & 1u)) >> 16);  // RNE
}

// ---------------- CSR build (by dst), once per call ----------------
// Single atomic pass: rank[e] = running count of dst[e]; cnt ends as degree.
__global__ void k_rank(const int* __restrict__ dst, int* __restrict__ cnt,
                       int* __restrict__ rank) {
    int e = blockIdx.x * 256 + threadIdx.x;
    if (e >= N_EDGES) return;
    rank[e] = atomicAdd(&cnt[dst[e]], 1);
}

__global__ void k_scan_block(const int* __restrict__ deg, int* __restrict__ rowptr,
                             int* __restrict__ bsum) {
    __shared__ int s[256];
    int i = blockIdx.x * 256 + threadIdx.x;
    int v = (i < N_NODES) ? deg[i] : 0;
    s[threadIdx.x] = v;
    __syncthreads();
    for (int off = 1; off < 256; off <<= 1) {
        int t = (threadIdx.x >= off) ? s[threadIdx.x - off] : 0;
        __syncthreads();
        s[threadIdx.x] += t;
        __syncthreads();
    }
    if (i < N_NODES) rowptr[i] = s[threadIdx.x] - v;
    if (threadIdx.x == 255) bsum[blockIdx.x] = s[255];
}

__global__ void k_scan_bsum(int* __restrict__ bsum, int nb) {
    __shared__ int s[256];
    int t = threadIdx.x;
    int v = (t < nb) ? bsum[t] : 0;
    s[t] = v;
    __syncthreads();
    for (int off = 1; off < 256; off <<= 1) {
        int tv = (t >= off) ? s[t - off] : 0;
        __syncthreads();
        s[t] += tv;
        __syncthreads();
    }
    if (t < nb) bsum[t] = s[t] - v;
}

__global__ void k_scan_add(int* __restrict__ rowptr, const int* __restrict__ bsum) {
    int i = blockIdx.x * 256 + threadIdx.x;
    if (i < N_NODES) rowptr[i] += bsum[blockIdx.x];
    if (i == 0) rowptr[N_NODES] = N_EDGES;
}

// ---- place: deterministic position, NO atomic — pure random 8B store ----
__global__ void k_place(const int* __restrict__ src, const int* __restrict__ dst,
                        const int* __restrict__ rank, const int* __restrict__ rowptr,
                        int2* __restrict__ csre) {
    int e = blockIdx.x * 256 + threadIdx.x;
    if (e >= N_EDGES) return;
    int p = rowptr[dst[e]] + rank[e];
    csre[p] = make_int2(src[e], e);
}

// ---- gather pass: random READS (L3-absorbed), sequential writes. ----
__global__ void k_gather(const int2* __restrict__ csre, const int* __restrict__ dstA,
                         const float* __restrict__ eattr, int* __restrict__ srcs,
                         int* __restrict__ pdst, ushort_t* __restrict__ ea) {
    int p = blockIdx.x * 256 + threadIdx.x;
    if (p >= N_EDGES) return;
    int2 se = csre[p];
    int e = se.y;
    srcs[p] = se.x;
    pdst[p] = dstA[e];
    const float4* er = (const float4*)(eattr + (size_t)e * ED);
    float4 v0 = er[0], v1 = er[1], v2 = er[2], v3 = er[3];
    uint4 w0, w1;
    w0.x = (uint_t)f2bf(v0.x) | ((uint_t)f2bf(v0.y) << 16);
    w0.y = (uint_t)f2bf(v0.z) | ((uint_t)f2bf(v0.w) << 16);
    w0.z = (uint_t)f2bf(v1.x) | ((uint_t)f2bf(v1.y) << 16);
    w0.w = (uint_t)f2bf(v1.z) | ((uint_t)f2bf(v1.w) << 16);
    w1.x = (uint_t)f2bf(v2.x) | ((uint_t)f2bf(v2.y) << 16);
    w1.y = (uint_t)f2bf(v2.z) | ((uint_t)f2bf(v2.w) << 16);
    w1.z = (uint_t)f2bf(v3.x) | ((uint_t)f2bf(v3.y) << 16);
    w1.w = (uint_t)f2bf(v3.z) | ((uint_t)f2bf(v3.w) << 16);
    uint4* ew = (uint4*)(ea + (size_t)p * ED);
    ew[0] = w0;
    ew[1] = w1;
}

// ---------------- proj: h = x @ proj_w + proj_b  (K=32) ----------------
__global__ __launch_bounds__(192) void k_proj(const float* __restrict__ x,
                                              const float* __restrict__ pw,
                                              const float* __restrict__ pb,
                                              float* __restrict__ h) {
    int t = threadIdx.x;
    int c = t % 96, half = t / 96;
    float wreg[ND];
#pragma unroll
    for (int k = 0; k < ND; k++) wreg[k] = pw[k * HID + c];
    float b = pb[c];
    int n0 = blockIdx.x * 16 + half * 8;
    for (int i = 0; i < 8; i += 2) {
        int na = n0 + i, nb = na + 1;
        const float4* xa = (const float4*)(x + (size_t)na * ND);
        const float4* xb = (const float4*)(x + (size_t)nb * ND);
        float accA = b, accB = b;
#pragma unroll
        for (int k4 = 0; k4 < ND / 4; k4++) {
            float4 va = xa[k4], vb = xb[k4];
            accA += va.x * wreg[4 * k4] + va.y * wreg[4 * k4 + 1] +
                    va.z * wreg[4 * k4 + 2] + va.w * wreg[4 * k4 + 3];
            accB += vb.x * wreg[4 * k4] + vb.y * wreg[4 * k4 + 1] +
                    vb.z * wreg[4 * k4 + 2] + vb.w * wreg[4 * k4 + 3];
        }
        h[(size_t)na * HID + c] = accA;
        h[(size_t)nb * HID + c] = accB;
    }
}

// ---- k_linlr_mfma: [xl|xr] = h @ [Wl|Wr] + [bl|br], bf16 out, MFMA ----
__global__ __launch_bounds__(256) void k_linlr_mfma(
    const float* __restrict__ h, const float* __restrict__ Wl,
    const float* __restrict__ bl, const float* __restrict__ Wr,
    const float* __restrict__ br, ushort_t* __restrict__ xl,
    ushort_t* __restrict__ xr) {
    __shared__ ushort_t sW[192 * 104];
    __shared__ float sB[192];
    int t = threadIdx.x;

    for (int idx = t; idx < 192 * 96; idx += 256) {
        int n = idx % 192, k = idx / 192;
        float v = (n < 96) ? Wl[k * 96 + n] : Wr[k * 96 + (n - 96)];
        sW[n * 104 + k] = f2bf(v);
    }
    if (t < 192) sB[t] = (t < 96) ? bl[t] : br[t - 96];
    __syncthreads();

    int wv = t >> 6, lane = t & 63;
    int m0 = blockIdx.x * 64 + wv * 16;
    if (m0 >= N_NODES) return;
    int m = lane & 15, quad = lane >> 4;

    bf16x8 afr[3];
    const float* hrow = h + (size_t)(m0 + m) * HID;
#pragma unroll
    for (int s = 0; s < 3; s++) {
        float4 v0 = *(const float4*)(hrow + s * 32 + quad * 8);
        float4 v1 = *(const float4*)(hrow + s * 32 + quad * 8 + 4);
        bf16x8 a;
        a[0] = (short)f2bf(v0.x); a[1] = (short)f2bf(v0.y);
        a[2] = (short)f2bf(v0.z); a[3] = (short)f2bf(v0.w);
        a[4] = (short)f2bf(v1.x); a[5] = (short)f2bf(v1.y);
        a[6] = (short)f2bf(v1.z); a[7] = (short)f2bf(v1.w);
        afr[s] = a;
    }

#pragma unroll
    for (int nt = 0; nt < 12; nt++) {
        int ch = nt * 16 + m;
        f32x4 acc = {0.f, 0.f, 0.f, 0.f};
#pragma unroll
        for (int s = 0; s < 3; s++) {
            bf16x8 bfr = *(const bf16x8*)(sW + (nt * 16 + m) * 104 + s * 32 + quad * 8);
            acc = __builtin_amdgcn_mfma_f32_16x16x32_bf16(afr[s], bfr, acc, 0, 0, 0);
        }
        float bias = sB[ch];
        ushort_t* dst = (ch < 96) ? (xl + (size_t)(m0 + quad * 4) * HID + ch)
                                  : (xr + (size_t)(m0 + quad * 4) * HID + (ch - 96));
#pragma unroll
        for (int r = 0; r < 4; r++)
            dst[(size_t)r * HID] = f2bf(acc[r] + bias);
    }
}

// ---- k_ev: edge-parallel attention weights via MFMA, CSR order, pipelined ----
// Channel remap: tile mc, A-row m -> physical channel (m>>2)*24 + mc*4 + (m&3).
// => lane (quad,col)'s D rows cover channels quad*24 + mc*4 + r: a CONTIGUOUS
// 24-ch block per lane (3 x uint4 gathers) and head == quad (logit summed
// entirely in-lane; no cross-lane shuffles; ev store = 1 coalesced dword).
__global__ __launch_bounds__(256) void k_ev(
    const ushort_t* __restrict__ xlb, const ushort_t* __restrict__ xrb,
    const ushort_t* __restrict__ ea, const int* __restrict__ srcs,
    const int* __restrict__ pdst, const float* __restrict__ WeL,
    const float* __restrict__ attL, float* __restrict__ evf) {
    int wid = blockIdx.x * 4 + (threadIdx.x >> 6);
    int lane = threadIdx.x & 63;
    if (wid >= N_EDGES / 128) return;
    int col = lane & 15, quad = lane >> 4;
    int comp = col & 1, base = col >> 1;

    // preload this wave's 128 srcs/pdst values (2 per lane)
    int2 sp = *(const int2*)(srcs + wid * 128 + 2 * lane);
    int2 dp = *(const int2*)(pdst + wid * 128 + 2 * lane);

    // wave-invariant A fragments (We^T, remapped channels)
    bf16x8 afr[6];
#pragma unroll
    for (int mc = 0; mc < 6; mc++) {
        bf16x8 a = {0, 0, 0, 0, 0, 0, 0, 0};
        if (quad < 2) {
            int ch = (col >> 2) * 24 + mc * 4 + (col & 3);
#pragma unroll
            for (int j = 0; j < 8; j++)
                a[j] = (short)f2bf(WeL[(quad * 8 + j) * HID + ch]);
        }
        afr[mc] = a;
    }
    // att for this lane's head (= quad)
    float attr[6][4];
#pragma unroll
    for (int mc = 0; mc < 6; mc++)
#pragma unroll
        for (int r = 0; r < 4; r++)
            attr[mc][r] = attL[quad * 24 + mc * 4 + r];

    // pipeline registers (2 batches in flight)
    bf16x8 bfr[2];
    uint4 xq[2][3], rq[2][3];

    auto getsd = [&](int b, int& sv, int& dv) {
        int sl = b * 8 + base;
        int sx = __shfl(sp.x, sl), sy = __shfl(sp.y, sl);
        int dx = __shfl(dp.x, sl), dy = __shfl(dp.y, sl);
        sv = comp ? sy : sx;
        dv = comp ? dy : dx;
    };
    auto issue = [&](int b, int pp) {
        int sv, dv;
        getsd(b, sv, dv);
        int p = wid * 128 + b * 16 + col;
        bf16x8 z8 = {0, 0, 0, 0, 0, 0, 0, 0};
        bfr[pp] = (quad < 2) ? *(const bf16x8*)(ea + (size_t)p * ED + quad * 8) : z8;
        const uint4* xp = (const uint4*)(xlb + (size_t)sv * HID + quad * 24);
        const uint4* rp = (const uint4*)(xrb + (size_t)dv * HID + quad * 24);
#pragma unroll
        for (int i = 0; i < 3; i++) {
            xq[pp][i] = xp[i];
            rq[pp][i] = rp[i];
        }
    };

    issue(0, 0);
#pragma unroll
    for (int b = 0; b < 8; b++) {
        int pp = b & 1;
        if (b < 7) issue(b + 1, pp ^ 1);

        f32x4 zero4 = {0.f, 0.f, 0.f, 0.f};
        f32x4 d[6];
#pragma unroll
        for (int mc = 0; mc < 6; mc++)
            d[mc] = __builtin_amdgcn_mfma_f32_16x16x32_bf16(afr[mc], bfr[pp], zero4, 0, 0, 0);

        uint_t ux[12] = {xq[pp][0].x, xq[pp][0].y, xq[pp][0].z, xq[pp][0].w,
                         xq[pp][1].x, xq[pp][1].y, xq[pp][1].z, xq[pp][1].w,
                         xq[pp][2].x, xq[pp][2].y, xq[pp][2].z, xq[pp][2].w};
        uint_t ur[12] = {rq[pp][0].x, rq[pp][0].y, rq[pp][0].z, rq[pp][0].w,
                         rq[pp][1].x, rq[pp][1].y, rq[pp][1].z, rq[pp][1].w,
                         rq[pp][2].x, rq[pp][2].y, rq[pp][2].z, rq[pp][2].w};
        float logit = 0.f;
#pragma unroll
        for (int mc = 0; mc < 6; mc++) {
            uint_t aL = ux[2 * mc], aH = ux[2 * mc + 1];
            uint_t rL = ur[2 * mc], rH = ur[2 * mc + 1];
            float x0 = bf2f((ushort_t)(aL & 0xffff)), x1 = bf2f((ushort_t)(aL >> 16));
            float x2 = bf2f((ushort_t)(aH & 0xffff)), x3 = bf2f((ushort_t)(aH >> 16));
            float r0 = bf2f((ushort_t)(rL & 0xffff)), r1 = bf2f((ushort_t)(rL >> 16));
            float r2 = bf2f((ushort_t)(rH & 0xffff)), r3 = bf2f((ushort_t)(rH >> 16));
            float z0 = x0 + r0 + d[mc][0]; z0 = z0 > 0.f ? z0 : 0.2f * z0;
            float z1 = x1 + r1 + d[mc][1]; z1 = z1 > 0.f ? z1 : 0.2f * z1;
            float z2 = x2 + r2 + d[mc][2]; z2 = z2 > 0.f ? z2 : 0.2f * z2;
            float z3 = x3 + r3 + d[mc][3]; z3 = z3 > 0.f ? z3 : 0.2f * z3;
            logit += z0 * attr[mc][0] + z1 * attr[mc][1] +
                     z2 * attr[mc][2] + z3 * attr[mc][3];
        }
        int p = wid * 128 + b * 16 + col;
        evf[4 * p + quad] = __expf(logit);   // coalesced: 64 lanes, 256B run
    }
}

// ---- k_agg: weighted sum + residual + LayerNorm. 8 edge-slots x 8 lanes
// (12 ch/lane, 3x8B loads), serial gather depth = deg/8, 2-stage pipeline. ----
__global__ __launch_bounds__(256) void k_agg(
    const ushort_t* __restrict__ xlb, const float* __restrict__ evf,
    const int* __restrict__ srcs, const int* __restrict__ rowptr,
    const float* __restrict__ convb, const float* __restrict__ lng,
    const float* __restrict__ lnb, float* __restrict__ h) {
    int lane = threadIdx.x & 63;
    int node = blockIdx.x * 4 + (threadIdx.x >> 6);
    int slot = lane >> 3, q = lane & 7;      // 8 slots x 8 channel-lanes
    int c0 = q * 12, head = q >> 1;          // 12 ch/lane; head = c0/24
    int beg = rowptr[node], end = rowptr[node + 1];
    int cnt = (end - beg + 7) >> 3;

    float n[12];
#pragma unroll
    for (int j = 0; j < 12; j++) n[j] = 0.f;
    float den = 0.f;

    if (cnt > 0) {
        int p = beg + slot;
        bool v = p < end;
        int pc = v ? p : beg;
        int src = srcs[pc];
        float evv = evf[4 * pc + head];
        const ushort_t* xp = xlb + (size_t)src * HID + c0;
        uint2 A0 = *(const uint2*)(xp);
        uint2 A1 = *(const uint2*)(xp + 4);
        uint2 A2 = *(const uint2*)(xp + 8);
        for (int it = 0; it < cnt; ++it) {
            int pn = beg + (it + 1) * 8 + slot;
            bool vn = pn < end;
            int pcn = vn ? pn : beg;
            int srcn = srcs[pcn];
            float evn = evf[4 * pcn + head];
            const ushort_t* xpn = xlb + (size_t)srcn * HID + c0;
            uint2 B0 = *(const uint2*)(xpn);
            uint2 B1 = *(const uint2*)(xpn + 4);
            uint2 B2 = *(const uint2*)(xpn + 8);

            float e = v ? evv : 0.f;
            n[0]  += e * bf2f((ushort_t)(A0.x & 0xffff));
            n[1]  += e * bf2f((ushort_t)(A0.x >> 16));
            n[2]  += e * bf2f((ushort_t)(A0.y & 0xffff));
            n[3]  += e * bf2f((ushort_t)(A0.y >> 16));
            n[4]  += e * bf2f((ushort_t)(A1.x & 0xffff));
            n[5]  += e * bf2f((ushort_t)(A1.x >> 16));
            n[6]  += e * bf2f((ushort_t)(A1.y & 0xffff));
            n[7]  += e * bf2f((ushort_t)(A1.y >> 16));
            n[8]  += e * bf2f((ushort_t)(A2.x & 0xffff));
            n[9]  += e * bf2f((ushort_t)(A2.x >> 16));
            n[10] += e * bf2f((ushort_t)(A2.y & 0xffff));
            n[11] += e * bf2f((ushort_t)(A2.y >> 16));
            den += e;

            v = vn; evv = evn;
            A0 = B0; A1 = B1; A2 = B2;
        }
    }
    // combine 8 slots
#pragma unroll
    for (int j = 0; j < 12; j++) {
        n[j] += __shfl_xor(n[j], 8);
        n[j] += __shfl_xor(n[j], 16);
        n[j] += __shfl_xor(n[j], 32);
    }
    den += __shfl_xor(den, 8);
    den += __shfl_xor(den, 16);
    den += __shfl_xor(den, 32);

    size_t nb = (size_t)node * HID + c0;
    float inv = 1.f / (den + 1e-16f);
    float4 h0 = *(const float4*)(h + nb);
    float4 h1 = *(const float4*)(h + nb + 4);
    float4 h2 = *(const float4*)(h + nb + 8);
    float vv[12] = {h0.x, h0.y, h0.z, h0.w, h1.x, h1.y, h1.z, h1.w,
                    h2.x, h2.y, h2.z, h2.w};
    float sm = 0.f;
#pragma unroll
    for (int j = 0; j < 12; j++) {
        vv[j] += n[j] * inv + convb[c0 + j];
        sm += vv[j];
    }
    sm += __shfl_xor(sm, 1); sm += __shfl_xor(sm, 2); sm += __shfl_xor(sm, 4);
    float mu = sm * (1.f / 96.f);
    float sv = 0.f;
#pragma unroll
    for (int j = 0; j < 12; j++) {
        vv[j] -= mu;
        sv += vv[j] * vv[j];
    }
    sv += __shfl_xor(sv, 1); sv += __shfl_xor(sv, 2); sv += __shfl_xor(sv, 4);
    float rstd = rsqrtf(sv * (1.f / 96.f) + 1e-5f);
    if (slot == 0) {
        float o[12];
#pragma unroll
        for (int j = 0; j < 12; j++)
            o[j] = vv[j] * rstd * lng[c0 + j] + lnb[c0 + j];
        *(float4*)(h + nb)     = make_float4(o[0], o[1], o[2], o[3]);
        *(float4*)(h + nb + 4) = make_float4(o[4], o[5], o[6], o[7]);
        *(float4*)(h + nb + 8) = make_float4(o[8], o[9], o[10], o[11]);
    }
}

// ---- k_head_mfma: out = gelu(h@W1+b1)@W2+b2 via MFMA ----
__global__ __launch_bounds__(256) void k_head_mfma(
    const float* __restrict__ h, const float* __restrict__ W1,
    const float* __restrict__ b1, const float* __restrict__ W2,
    const float* __restrict__ b2, float* __restrict__ out) {
    __shared__ ushort_t sW[48 * 104];
    __shared__ float sB1[48];
    __shared__ float sW2[48];
    int t = threadIdx.x;
    for (int idx = t; idx < 48 * 96; idx += 256) {
        int j = idx % 48, k = idx / 48;
        sW[j * 104 + k] = f2bf(W1[k * 48 + j]);
    }
    if (t < 48) { sB1[t] = b1[t]; sW2[t] = W2[t]; }
    __syncthreads();

    int wv = t >> 6, lane = t & 63;
    int m0 = blockIdx.x * 64 + wv * 16;
    if (m0 >= N_NODES) return;
    int col = lane & 15, quad = lane >> 4;

    bf16x8 afr[3];
    const float* hrow = h + (size_t)(m0 + col) * HID;
#pragma unroll
    for (int s = 0; s < 3; s++) {
        float4 v0 = *(const float4*)(hrow + s * 32 + quad * 8);
        float4 v1 = *(const float4*)(hrow + s * 32 + quad * 8 + 4);
        bf16x8 a;
        a[0] = (short)f2bf(v0.x); a[1] = (short)f2bf(v0.y);
        a[2] = (short)f2bf(v0.z); a[3] = (short)f2bf(v0.w);
        a[4] = (short)f2bf(v1.x); a[5] = (short)f2bf(v1.y);
        a[6] = (short)f2bf(v1.z); a[7] = (short)f2bf(v1.w);
        afr[s] = a;
    }

    const float inv_sqrt2 = 0.70710678118654752f;
    float y0 = 0.f, y1 = 0.f, y2 = 0.f, y3 = 0.f;
#pragma unroll
    for (int nt = 0; nt < 3; nt++) {
        f32x4 acc = {0.f, 0.f, 0.f, 0.f};
#pragma unroll
        for (int s = 0; s < 3; s++) {
            bf16x8 bfr = *(const bf16x8*)(sW + (nt * 16 + col) * 104 + s * 32 + quad * 8);
            acc = __builtin_amdgcn_mfma_f32_16x16x32_bf16(afr[s], bfr, acc, 0, 0, 0);
        }
        int ch = nt * 16 + col;
        float bias = sB1[ch], w2 = sW2[ch];
        float v, g;
        v = acc[0] + bias; g = 0.5f * v * (1.f + erff(v * inv_sqrt2)); y0 += g * w2;
        v = acc[1] + bias; g = 0.5f * v * (1.f + erff(v * inv_sqrt2)); y1 += g * w2;
        v = acc[2] + bias; g = 0.5f * v * (1.f + erff(v * inv_sqrt2)); y2 += g * w2;
        v = acc[3] + bias; g = 0.5f * v * (1.f + erff(v * inv_sqrt2)); y3 += g * w2;
    }
    y0 += __shfl_xor(y0, 1); y0 += __shfl_xor(y0, 2);
    y0 += __shfl_xor(y0, 4); y0 += __shfl_xor(y0, 8);
    y1 += __shfl_xor(y1, 1); y1 += __shfl_xor(y1, 2);
    y1 += __shfl_xor(y1, 4); y1 += __shfl_xor(y1, 8);
    y2 += __shfl_xor(y2, 1); y2 += __shfl_xor(y2, 2);
    y2 += __shfl_xor(y2, 4); y2 += __shfl_xor(y2, 8);
    y3 += __shfl_xor(y3, 1); y3 += __shfl_xor(y3, 2);
    y3 += __shfl_xor(y3, 4); y3 += __shfl_xor(y3, 8);
    if (col == 0) {
        float bb = b2[0];
        out[m0 + quad * 4 + 0] = y0 + bb;
        out[m0 + quad * 4 + 1] = y1 + bb;
        out[m0 + quad * 4 + 2] = y2 + bb;
        out[m0 + quad * 4 + 3] = y3 + bb;
    }
}

extern "C" void kernel_launch(void* const* d_in, const int* in_sizes, int n_in,
                              void* d_out, int out_size, void* d_ws, size_t ws_size,
                              hipStream_t stream) {
    const float* x       = (const float*)d_in[0];
    const int*   eidx    = (const int*)  d_in[1];
    const float* eattr   = (const float*)d_in[2];
    const float* proj_w  = (const float*)d_in[3];
    const float* proj_b  = (const float*)d_in[4];
    const float* lin_l_w = (const float*)d_in[5];
    const float* lin_l_b = (const float*)d_in[6];
    const float* lin_r_w = (const float*)d_in[7];
    const float* lin_r_b = (const float*)d_in[8];
    const float* lin_e_w = (const float*)d_in[9];
    const float* att     = (const float*)d_in[10];
    const float* conv_b  = (const float*)d_in[11];
    const float* ln_g    = (const float*)d_in[12];
    const float* ln_b    = (const float*)d_in[13];
    const float* head_w1 = (const float*)d_in[14];
    const float* head_b1 = (const float*)d_in[15];
    const float* head_w2 = (const float*)d_in[16];
    const float* head_b2 = (const float*)d_in[17];
    float* out = (float*)d_out;

    char* p = (char*)d_ws;
    auto alloc = [&](size_t bytes) -> char* {
        char* r = p;
        p += (bytes + 255) & ~size_t(255);
        return r;
    };
    float*    h      = (float*)alloc(sizeof(float) * (size_t)N_NODES * HID);
    ushort_t* xl     = (ushort_t*)alloc(2 * (size_t)N_NODES * HID);
    ushort_t* xr     = (ushort_t*)alloc(2 * (size_t)N_NODES * HID);
    int*      cnt    = (int*)alloc(4 * (size_t)N_NODES);
    int*      rank   = (int*)alloc(4 * (size_t)N_EDGES);
    int*      rowptr = (int*)alloc(4 * (size_t)(N_NODES + 1));
    int*      bsum   = (int*)alloc(4 * 256);
    int2*     csre   = (int2*)alloc(8 * (size_t)N_EDGES);
    int*      srcs   = (int*)alloc(4 * ((size_t)N_EDGES + 256));
    int*      pdst   = (int*)alloc(4 * ((size_t)N_EDGES + 256));
    ushort_t* ea_csr = (ushort_t*)alloc(2 * (size_t)N_EDGES * ED);
    float*    ev     = (float*)alloc(16 * (size_t)N_EDGES);

    const int* srcA = eidx;
    const int* dstA = eidx + N_EDGES;

    int ebl = (N_EDGES + 255) / 256;   // 3125
    int nbl = (N_NODES + 255) / 256;   // 196

    hipMemsetAsync(cnt, 0, 4 * (size_t)N_NODES, stream);
    k_rank<<<ebl, 256, 0, stream>>>(dstA, cnt, rank);
    k_scan_block<<<nbl, 256, 0, stream>>>(cnt, rowptr, bsum);
    k_scan_bsum<<<1, 256, 0, stream>>>(bsum, nbl);
    k_scan_add<<<nbl, 256, 0, stream>>>(rowptr, bsum);
    k_place<<<ebl, 256, 0, stream>>>(srcA, dstA, rank, rowptr, csre);
    k_gather<<<ebl, 256, 0, stream>>>(csre, dstA, eattr, srcs, pdst, ea_csr);

    k_proj<<<N_NODES / 16, 192, 0, stream>>>(x, proj_w, proj_b, h);
    for (int l = 0; l < NLAYER; l++) {
        k_linlr_mfma<<<(N_NODES + 63) / 64, 256, 0, stream>>>(
            h, lin_l_w + (size_t)l * HID * HID, lin_l_b + (size_t)l * HID,
            lin_r_w + (size_t)l * HID * HID, lin_r_b + (size_t)l * HID, xl, xr);
        k_ev<<<1563, 256, 0, stream>>>(xl, xr, ea_csr, srcs, pdst,
                                       lin_e_w + (size_t)l * ED * HID,
                                       att + (size_t)l * HID, ev);
        k_agg<<<N_NODES / 4, 256, 0, stream>>>(
            xl, ev, srcs, rowptr, conv_b + (size_t)l * HID,
            ln_g + (size_t)l * HID, ln_b + (size_t)l * HID, h);
    }
    k_head_mfma<<<(N_NODES + 63) / 64, 256, 0, stream>>>(h, head_w1, head_b1,
                                                         head_w2, head_b2, out);
}